// Round 6
// baseline (297.559 us; speedup 1.0000x reference)
//
#include <hip/hip_runtime.h>

// AttentionLoRA: B=1, S=4096, D=1024, H=16, HD=64.
// Pipeline: cvt_all(f32->bf16 + bias pack) -> QKV NT-GEMM (ping-pong staged, scatter
// epilogue) -> RoPE (q pre-scaled by 0.125*log2e) -> V transpose -> flash attention
// (128-row q blocks / 32 rows per wave, complementary-qb swizzle, K+V DMA-staged in
//  LDS, exp2 softmax, no running max) -> out-proj GEMM (f32 out).

#define S_LEN 4096
#define DIM   1024
#define NH    16
#define HD    64

typedef __attribute__((ext_vector_type(8))) short bf16x8;   // 8 bf16 = 4 VGPRs
typedef __attribute__((ext_vector_type(4))) float f32x4;

__device__ __forceinline__ unsigned short f2b(float f) {
  union { float f; unsigned int u; } v; v.f = f;
  unsigned int r = (v.u + 0x7fffu + ((v.u >> 16) & 1u)) >> 16;  // RNE
  return (unsigned short)r;
}
__device__ __forceinline__ float b2f(unsigned short h) {
  union { unsigned int u; float f; } v; v.u = ((unsigned int)h) << 16;
  return v.f;
}
// pack two f32 -> two bf16 by truncation (p in [0,1]; <=1ulp)
__device__ __forceinline__ unsigned int pk2t(float a, float b) {
  union { float f; unsigned int u; } x, y; x.f = a; y.f = b;
  return (x.u >> 16) | (y.u & 0xffff0000u);
}
__device__ __forceinline__ void gload16(const void* g, void* l) {
  __builtin_amdgcn_global_load_lds(
      (const __attribute__((address_space(1))) unsigned int*)g,
      (__attribute__((address_space(3))) unsigned int*)l, 16, 0, 0);
}
__device__ __forceinline__ f32x4 fzero4() { f32x4 z = {0.f, 0.f, 0.f, 0.f}; return z; }

// ---------------- fused f32->bf16 convert (x, wq, wk, wv, wo) + bias pack ----------
__global__ void cvt_all(const float* __restrict__ x, const float* __restrict__ wq,
                        const float* __restrict__ wk, const float* __restrict__ wv,
                        const float* __restrict__ wo, const float* __restrict__ qb,
                        const float* __restrict__ kb, const float* __restrict__ vbs,
                        const float* __restrict__ ob, unsigned short* __restrict__ xb,
                        unsigned short* __restrict__ wqkvb, unsigned short* __restrict__ wobb,
                        float* __restrict__ biasq, float* __restrict__ biaso) {
  int i = blockIdx.x * 256 + threadIdx.x;  // float4 index
  if (i < 2097152) {
    const float* src; unsigned short* dst; int off;
    if (i < 1048576)      { src = x;  dst = xb;              off = i; }
    else if (i < 1310720) { src = wq; dst = wqkvb;           off = i - 1048576; }
    else if (i < 1572864) { src = wk; dst = wqkvb + 1048576; off = i - 1310720; }
    else if (i < 1835008) { src = wv; dst = wqkvb + 2097152; off = i - 1572864; }
    else                  { src = wo; dst = wobb;            off = i - 1835008; }
    float4 v = ((const float4*)src)[off];
    unsigned int lo = (unsigned int)f2b(v.x) | ((unsigned int)f2b(v.y) << 16);
    unsigned int hi = (unsigned int)f2b(v.z) | ((unsigned int)f2b(v.w) << 16);
    ((uint2*)dst)[off] = make_uint2(lo, hi);
  } else if (i < 2097152 + 1024) {
    int j = i - 2097152;
    if (j < 256)      ((float4*)biasq)[j]              = ((const float4*)qb)[j];
    else if (j < 512) ((float4*)(biasq + 1024))[j-256] = ((const float4*)kb)[j-256];
    else if (j < 768) ((float4*)(biasq + 2048))[j-512] = ((const float4*)vbs)[j-512];
    else              ((float4*)biaso)[j-768]          = ((const float4*)ob)[j-768];
  }
}

// ---------------- NT GEMM: C[m,n] = sum_k A[m,k]*B[n,k] + bias[n] ----------------
// 128x128 tile, BK=32, 4 waves each 64x64 (4x4 of 16x16x32 MFMA). Ping-pong LDS
// staging, one barrier per K-iter (DMA for t+1 issued after barrier t).
// mode 0: scatter to q/k/v bf16 (h,s,hd).  mode 1: f32 row-major out.
__global__ __launch_bounds__(256) void gemm_nt(
    const unsigned short* __restrict__ A, const unsigned short* __restrict__ B,
    const float* __restrict__ bias, float* __restrict__ outF,
    unsigned short* __restrict__ dq, unsigned short* __restrict__ dk,
    unsigned short* __restrict__ dv, int M, int N, int K, int mode) {
  __shared__ alignas(16) unsigned short sA[2][128 * 32];
  __shared__ alignas(16) unsigned short sB[2][128 * 32];
  const int tid = threadIdx.x;
  const int lane = tid & 63, wave = tid >> 6;
  const int ln = lane & 15, quad = lane >> 4;
  const int bm = blockIdx.x * 128, bn = blockIdx.y * 128;
  const int wr = (wave >> 1) * 64, wc = (wave & 1) * 64;

  f32x4 acc[4][4];
#pragma unroll
  for (int i = 0; i < 4; ++i)
#pragma unroll
    for (int j = 0; j < 4; ++j) acc[i][j] = fzero4();

  // preload K-tile 0 into buffer 0
#pragma unroll
  for (int i = 0; i < 2; ++i) {
    int o = (i * 256 + tid) * 16;
    int e = o >> 1;
    int row = e >> 5, col = e & 31;
    gload16(A + (size_t)(bm + row) * K + col, (char*)sA[0] + o);
    gload16(B + (size_t)(bn + row) * K + col, (char*)sB[0] + o);
  }

  int buf = 0;
  for (int k0 = 0; k0 < K; k0 += 32, buf ^= 1) {
    __syncthreads();  // drains DMA for current buf; guards other buf vs old readers
    if (k0 + 32 < K) {
#pragma unroll
      for (int i = 0; i < 2; ++i) {
        int o = (i * 256 + tid) * 16;
        int e = o >> 1;
        int row = e >> 5, col = e & 31;
        gload16(A + (size_t)(bm + row) * K + k0 + 32 + col, (char*)sA[buf ^ 1] + o);
        gload16(B + (size_t)(bn + row) * K + k0 + 32 + col, (char*)sB[buf ^ 1] + o);
      }
    }
    bf16x8 af[4], bfr[4];
#pragma unroll
    for (int i = 0; i < 4; ++i) {
      af[i]  = *(const bf16x8*)&sA[buf][(wr + i * 16 + ln) * 32 + quad * 8];
      bfr[i] = *(const bf16x8*)&sB[buf][(wc + i * 16 + ln) * 32 + quad * 8];
    }
#pragma unroll
    for (int i = 0; i < 4; ++i)
#pragma unroll
      for (int j = 0; j < 4; ++j)
        acc[i][j] = __builtin_amdgcn_mfma_f32_16x16x32_bf16(af[i], bfr[j], acc[i][j], 0, 0, 0);
  }

  if (mode == 1) {
#pragma unroll
    for (int i = 0; i < 4; ++i)
#pragma unroll
      for (int j = 0; j < 4; ++j) {
        int n = bn + wc + j * 16 + ln;
        float bi = bias[n];
#pragma unroll
        for (int r = 0; r < 4; ++r) {
          int m = bm + wr + i * 16 + quad * 4 + r;
          outF[(size_t)m * N + n] = acc[i][j][r] + bi;
        }
      }
  } else {
    const int bufi = bn >> 10;
    unsigned short* const base = bufi == 0 ? dq : (bufi == 1 ? dk : dv);
    const int hq = ((bn & 1023) + wc) >> 6;  // head index, wave-uniform
#pragma unroll
    for (int i = 0; i < 4; ++i)
#pragma unroll
      for (int j = 0; j < 4; ++j) {
        int n = bn + wc + j * 16 + ln;
        float bi = bias[n];
        int hd = j * 16 + ln;
#pragma unroll
        for (int r = 0; r < 4; ++r) {
          int m = bm + wr + i * 16 + quad * 4 + r;
          base[((size_t)(hq * S_LEN + m)) * HD + hd] = f2b(acc[i][j][r] + bi);
        }
      }
  }
}

// ---------------- RoPE in-place on q,k (h,s,hd); q pre-scaled by 0.125*log2e ------
__global__ void rope_kernel(unsigned short* __restrict__ q, unsigned short* __restrict__ k,
                            const float* __restrict__ fc, const float* __restrict__ fs) {
  int idx = blockIdx.x * 256 + threadIdx.x;  // 2 * 16*4096*8
  const int P = NH * S_LEN * 8;
  bool isq = idx < P;
  unsigned short* t = isq ? q : k;
  int i = isq ? idx : idx - P;
  int g = i & 7;
  int s = (i >> 3) & 4095;
  int h = i >> 15;
  const float scale = isq ? 0.180336880f : 1.0f;  // (1/8)*log2(e) folded into q
  float4 c4 = *(const float4*)&fc[s * 32 + g * 4];
  float4 s4 = *(const float4*)&fs[s * 32 + g * 4];
  uint4* p = (uint4*)&t[((size_t)(h * S_LEN + s)) * HD + g * 8];
  uint4 pv = *p;
  auto rot = [&](unsigned int w, float c, float sn) -> unsigned int {
    float x0 = b2f((unsigned short)(w & 0xffffu));
    float x1 = b2f((unsigned short)(w >> 16));
    float o0 = (x0 * c - x1 * sn) * scale;
    float o1 = (x0 * sn + x1 * c) * scale;
    return (unsigned int)f2b(o0) | ((unsigned int)f2b(o1) << 16);
  };
  pv.x = rot(pv.x, c4.x, s4.x);
  pv.y = rot(pv.y, c4.y, s4.y);
  pv.z = rot(pv.z, c4.z, s4.z);
  pv.w = rot(pv.w, c4.w, s4.w);
  *p = pv;
}

// ---------------- V transpose: (h,s,hd) -> (h,hd,s), vectorized both global sides --
__global__ void transpose_v(const unsigned short* __restrict__ v, unsigned short* __restrict__ vt) {
  __shared__ unsigned short t[64][72];  // row stride 144B (multiple of 16) -> aligned b128
  const int h = blockIdx.y;
  const int s0 = blockIdx.x * 64;
  const int tid = threadIdx.x;
  const int r = tid >> 2, c0 = (tid & 3) * 16;
  const uint4* src = (const uint4*)(v + ((size_t)h * S_LEN + s0 + r) * HD + c0);
  uint4 a = src[0], b = src[1];
  *(uint4*)&t[r][c0] = a;
  *(uint4*)&t[r][c0 + 8] = b;
  __syncthreads();
  union { unsigned short u[16]; uint4 q[2]; } o;
#pragma unroll
  for (int j = 0; j < 16; ++j) o.u[j] = t[c0 + j][r];
  uint4* dst = (uint4*)(vt + ((size_t)h * HD + r) * S_LEN + s0 + c0);
  dst[0] = o.q[0];
  dst[1] = o.q[1];
}

// ---------------- LDS swizzled 16B reads (chunk XOR to spread banks) ----------------
__device__ __forceinline__ bf16x8 lds_swzK(const unsigned short* s, int row, int chunk) {
  int byte = row * 128 + ((chunk ^ ((row >> 2) & 7)) << 4);
  return *(const bf16x8*)((const char*)s + byte);
}
__device__ __forceinline__ bf16x8 lds_swzV(const unsigned short* s, int row, int chunk) {
  int byte = row * 128 + ((chunk ^ (row & 7)) << 4);
  return *(const bf16x8*)((const char*)s + byte);
}

// ---------------- Flash attention, causal, exp2 softmax (no running max) ----------
// R5 structure (K+V DMA-staged, the measured-fastest) with 128-row q blocks:
// 32 q-rows/wave (mt=2) halves total device tile-steps (33,280 -> 16,896) while
// KV staging + K/V LDS reads per step stay constant — the LDS-bound loop's cost
// per step grows only by P traffic (~25%). Grid (32,16) = 512 blocks;
// complementary qb swizzle: blocks c and c+256 (same CU under round-robin) get
// qb = x vs 31-x -> every CU totals 66 tile-steps.
// Score col ln of tile t <-> kv row 4*ln+t (P writes contiguous b64/lane).
// Mask only on diagonal-straddling tiles; waves entirely above a tile skip compute
// (barriers still executed by all waves). l via MFMA-with-ones (C-layout like O).
__global__ __launch_bounds__(256, 4) void flash_kernel(
    const unsigned short* __restrict__ qg, const unsigned short* __restrict__ kg,
    const unsigned short* __restrict__ vtg, unsigned short* __restrict__ attn) {
  __shared__ alignas(16) unsigned short sK[64 * 64];
  __shared__ alignas(16) unsigned short sV[64 * 64];
  __shared__ alignas(16) unsigned short sP[4 * 32 * 72];  // per-wave 32x64, stride 72

  const int tid = threadIdx.x;
  const int lane = tid & 63, wave = tid >> 6;
  const int ln = lane & 15, quad = lane >> 4;
  const int h = blockIdx.y;
  const int qb = ((h >> 3) & 1) ? (int)blockIdx.x : 31 - (int)blockIdx.x;
  const int q0 = qb * 128;
  const int qrow = q0 + wave * 32;

  const unsigned short* qh = qg + (size_t)h * (S_LEN * HD);
  const unsigned short* kh = kg + (size_t)h * (S_LEN * HD);
  const unsigned short* vh = vtg + (size_t)h * (HD * S_LEN);

  // Q fragments (A-layout: m=ln, k=quad*8+j), 32 rows/wave
  bf16x8 qf[2][2];
#pragma unroll
  for (int mt = 0; mt < 2; ++mt)
#pragma unroll
    for (int ks = 0; ks < 2; ++ks)
      qf[mt][ks] = *(const bf16x8*)(qh + (size_t)(qrow + mt * 16 + ln) * HD + ks * 32 + quad * 8);

  f32x4 o_acc[2][4];
  f32x4 l_acc[2];
#pragma unroll
  for (int mt = 0; mt < 2; ++mt) {
    l_acc[mt] = fzero4();
#pragma unroll
    for (int t = 0; t < 4; ++t) o_acc[mt][t] = fzero4();
  }
  bf16x8 ones;
#pragma unroll
  for (int j = 0; j < 8; ++j) ones[j] = (short)0x3F80;  // bf16 1.0

  unsigned short* pw = &sP[wave * (32 * 72)];
  const int nkv = 2 * qb + 2;

  for (int kt = 0; kt < nkv; ++kt) {
    const int kv0 = kt * 64;
    __syncthreads();  // protect sK/sV from previous iteration's readers
#pragma unroll
    for (int i = 0; i < 2; ++i) {
      int ob = (i * 256 + tid) * 16;
      int row = ob >> 7;
      int ch = (ob >> 4) & 7;
      gload16(kh + (size_t)(kv0 + row) * HD + ((ch ^ ((row >> 2) & 7)) << 3), (char*)sK + ob);
      gload16(vh + (size_t)row * S_LEN + kv0 + ((ch ^ (row & 7)) << 3), (char*)sV + ob);
    }
    __syncthreads();

    if (kv0 > qrow + 31) continue;  // wave entirely above tile (both barriers done)

    // S = Q K^T (tile t col ln <-> kv row 4*ln+t)
    f32x4 sc[2][4];
#pragma unroll
    for (int mt = 0; mt < 2; ++mt)
#pragma unroll
      for (int t = 0; t < 4; ++t) sc[mt][t] = fzero4();
#pragma unroll
    for (int t = 0; t < 4; ++t) {
      int krow = ln * 4 + t;
      bf16x8 kb0 = lds_swzK(sK, krow, quad);
      bf16x8 kb1 = lds_swzK(sK, krow, 4 + quad);
#pragma unroll
      for (int mt = 0; mt < 2; ++mt) {
        sc[mt][t] = __builtin_amdgcn_mfma_f32_16x16x32_bf16(qf[mt][0], kb0, sc[mt][t], 0, 0, 0);
        sc[mt][t] = __builtin_amdgcn_mfma_f32_16x16x32_bf16(qf[mt][1], kb1, sc[mt][t], 0, 0, 0);
      }
    }

    // p = exp2(s); mask only when tile straddles this wave's rows; truncation pack
    if (kv0 + 63 > qrow) {
#pragma unroll
      for (int mt = 0; mt < 2; ++mt)
#pragma unroll
        for (int r = 0; r < 4; ++r) {
          int row = qrow + mt * 16 + quad * 4 + r;
          int colb = kv0 + ln * 4;
          float p0 = (colb + 0 <= row) ? __builtin_amdgcn_exp2f(sc[mt][0][r]) : 0.0f;
          float p1 = (colb + 1 <= row) ? __builtin_amdgcn_exp2f(sc[mt][1][r]) : 0.0f;
          float p2 = (colb + 2 <= row) ? __builtin_amdgcn_exp2f(sc[mt][2][r]) : 0.0f;
          float p3 = (colb + 3 <= row) ? __builtin_amdgcn_exp2f(sc[mt][3][r]) : 0.0f;
          *(uint2*)&pw[(mt * 16 + quad * 4 + r) * 72 + ln * 4] =
              make_uint2(pk2t(p0, p1), pk2t(p2, p3));
        }
    } else {
#pragma unroll
      for (int mt = 0; mt < 2; ++mt)
#pragma unroll
        for (int r = 0; r < 4; ++r) {
          float p0 = __builtin_amdgcn_exp2f(sc[mt][0][r]);
          float p1 = __builtin_amdgcn_exp2f(sc[mt][1][r]);
          float p2 = __builtin_amdgcn_exp2f(sc[mt][2][r]);
          float p3 = __builtin_amdgcn_exp2f(sc[mt][3][r]);
          *(uint2*)&pw[(mt * 16 + quad * 4 + r) * 72 + ln * 4] =
              make_uint2(pk2t(p0, p1), pk2t(p2, p3));
        }
    }

    // P fragments (A-layout), per-wave region -> no barrier needed
    bf16x8 pa[2][2];
#pragma unroll
    for (int mt = 0; mt < 2; ++mt) {
      pa[mt][0] = *(const bf16x8*)&pw[(mt * 16 + ln) * 72 + quad * 8];
      pa[mt][1] = *(const bf16x8*)&pw[(mt * 16 + ln) * 72 + 32 + quad * 8];
    }

    // l += P @ ones
#pragma unroll
    for (int mt = 0; mt < 2; ++mt) {
      l_acc[mt] = __builtin_amdgcn_mfma_f32_16x16x32_bf16(pa[mt][0], ones, l_acc[mt], 0, 0, 0);
      l_acc[mt] = __builtin_amdgcn_mfma_f32_16x16x32_bf16(pa[mt][1], ones, l_acc[mt], 0, 0, 0);
    }

    // O += P @ V
#pragma unroll
    for (int t = 0; t < 4; ++t) {
      int vrow = t * 16 + ln;
      bf16x8 vb0 = lds_swzV(sV, vrow, quad);
      bf16x8 vb1 = lds_swzV(sV, vrow, 4 + quad);
#pragma unroll
      for (int mt = 0; mt < 2; ++mt) {
        o_acc[mt][t] = __builtin_amdgcn_mfma_f32_16x16x32_bf16(pa[mt][0], vb0, o_acc[mt][t], 0, 0, 0);
        o_acc[mt][t] = __builtin_amdgcn_mfma_f32_16x16x32_bf16(pa[mt][1], vb1, o_acc[mt][t], 0, 0, 0);
      }
    }
  }

  // epilogue: attn[s, h*64+hd] = O/l (bf16)
#pragma unroll
  for (int mt = 0; mt < 2; ++mt) {
    float inv[4];
#pragma unroll
    for (int r = 0; r < 4; ++r) inv[r] = 1.0f / l_acc[mt][r];
#pragma unroll
    for (int t = 0; t < 4; ++t)
#pragma unroll
      for (int r = 0; r < 4; ++r) {
        int row = qrow + mt * 16 + quad * 4 + r;
        attn[(size_t)row * DIM + h * HD + t * 16 + ln] = f2b(o_acc[mt][t][r] * inv[r]);
      }
  }
}

extern "C" void kernel_launch(void* const* d_in, const int* in_sizes, int n_in,
                              void* d_out, int out_size, void* d_ws, size_t ws_size,
                              hipStream_t stream) {
  const float* x    = (const float*)d_in[0];
  const float* fc   = (const float*)d_in[2];
  const float* fs   = (const float*)d_in[3];
  const float* wqw  = (const float*)d_in[5];
  const float* wqb  = (const float*)d_in[6];
  const float* wkw  = (const float*)d_in[7];
  const float* wkb  = (const float*)d_in[8];
  const float* wvw  = (const float*)d_in[9];
  const float* wvb  = (const float*)d_in[10];
  const float* wow  = (const float*)d_in[11];
  const float* wobf = (const float*)d_in[12];
  float* out = (float*)d_out;

  char* ws = (char*)d_ws;
  const size_t MB = (size_t)1 << 20;
  unsigned short* xb    = (unsigned short*)(ws + 0);
  unsigned short* wqkvb = (unsigned short*)(ws + 8 * MB);
  unsigned short* wobb  = (unsigned short*)(ws + 16 * MB);
  float* biasq = (float*)(ws + 18 * MB);
  float* biaso = (float*)(ws + 18 * MB + 65536);
  unsigned short* qb_ = (unsigned short*)(ws + 19 * MB);
  unsigned short* kb_ = (unsigned short*)(ws + 27 * MB);
  unsigned short* vb_ = (unsigned short*)(ws + 35 * MB);
  unsigned short* vt  = (unsigned short*)(ws + 8 * MB);  // aliases wqkvb (dead after QKV GEMM)
  unsigned short* attn = (unsigned short*)(ws + 0);      // aliases xb (dead after QKV GEMM)

  cvt_all<<<8196, 256, 0, stream>>>(x, wqw, wkw, wvw, wow, wqb, wkb, wvb, wobf,
                                    xb, wqkvb, wobb, biasq, biaso);
  gemm_nt<<<dim3(32, 24), 256, 0, stream>>>(xb, wqkvb, biasq, nullptr, qb_, kb_, vb_,
                                            4096, 3072, 1024, 0);
  rope_kernel<<<4096, 256, 0, stream>>>(qb_, kb_, fc, fs);
  transpose_v<<<dim3(64, 16), 256, 0, stream>>>(vb_, vt);
  flash_kernel<<<dim3(32, 16), 256, 0, stream>>>(qb_, kb_, vt, attn);
  gemm_nt<<<dim3(32, 8), 256, 0, stream>>>(attn, wobb, biaso, out, nullptr, nullptr, nullptr,
                                           4096, 1024, 1024, 1);
}

// Round 7
// 290.969 us; speedup vs baseline: 1.0227x; 1.0227x over previous
//
#include <hip/hip_runtime.h>

// AttentionLoRA: B=1, S=4096, D=1024, H=16, HD=64.
// Pipeline: cvt_all(f32->bf16 + bias pack) -> QKV NT-GEMM (ping-pong staged, scatter
// epilogue) -> RoPE (q pre-scaled by 0.125*log2e) -> V transpose -> flash attention
// (64-row q blocks, 2 waves x 32 rows [LDS amortization without grid shrink],
//  complementary-qb swizzle, K+V DMA-staged in LDS, exp2 softmax, no running max)
// -> out-proj GEMM (f32 out).

#define S_LEN 4096
#define DIM   1024
#define NH    16
#define HD    64

typedef __attribute__((ext_vector_type(8))) short bf16x8;   // 8 bf16 = 4 VGPRs
typedef __attribute__((ext_vector_type(4))) float f32x4;

__device__ __forceinline__ unsigned short f2b(float f) {
  union { float f; unsigned int u; } v; v.f = f;
  unsigned int r = (v.u + 0x7fffu + ((v.u >> 16) & 1u)) >> 16;  // RNE
  return (unsigned short)r;
}
__device__ __forceinline__ float b2f(unsigned short h) {
  union { unsigned int u; float f; } v; v.u = ((unsigned int)h) << 16;
  return v.f;
}
// pack two f32 -> two bf16 by truncation (p in [0,1]; <=1ulp)
__device__ __forceinline__ unsigned int pk2t(float a, float b) {
  union { float f; unsigned int u; } x, y; x.f = a; y.f = b;
  return (x.u >> 16) | (y.u & 0xffff0000u);
}
__device__ __forceinline__ void gload16(const void* g, void* l) {
  __builtin_amdgcn_global_load_lds(
      (const __attribute__((address_space(1))) unsigned int*)g,
      (__attribute__((address_space(3))) unsigned int*)l, 16, 0, 0);
}
__device__ __forceinline__ f32x4 fzero4() { f32x4 z = {0.f, 0.f, 0.f, 0.f}; return z; }

// ---------------- fused f32->bf16 convert (x, wq, wk, wv, wo) + bias pack ----------
__global__ void cvt_all(const float* __restrict__ x, const float* __restrict__ wq,
                        const float* __restrict__ wk, const float* __restrict__ wv,
                        const float* __restrict__ wo, const float* __restrict__ qb,
                        const float* __restrict__ kb, const float* __restrict__ vbs,
                        const float* __restrict__ ob, unsigned short* __restrict__ xb,
                        unsigned short* __restrict__ wqkvb, unsigned short* __restrict__ wobb,
                        float* __restrict__ biasq, float* __restrict__ biaso) {
  int i = blockIdx.x * 256 + threadIdx.x;  // float4 index
  if (i < 2097152) {
    const float* src; unsigned short* dst; int off;
    if (i < 1048576)      { src = x;  dst = xb;              off = i; }
    else if (i < 1310720) { src = wq; dst = wqkvb;           off = i - 1048576; }
    else if (i < 1572864) { src = wk; dst = wqkvb + 1048576; off = i - 1310720; }
    else if (i < 1835008) { src = wv; dst = wqkvb + 2097152; off = i - 1572864; }
    else                  { src = wo; dst = wobb;            off = i - 1835008; }
    float4 v = ((const float4*)src)[off];
    unsigned int lo = (unsigned int)f2b(v.x) | ((unsigned int)f2b(v.y) << 16);
    unsigned int hi = (unsigned int)f2b(v.z) | ((unsigned int)f2b(v.w) << 16);
    ((uint2*)dst)[off] = make_uint2(lo, hi);
  } else if (i < 2097152 + 1024) {
    int j = i - 2097152;
    if (j < 256)      ((float4*)biasq)[j]              = ((const float4*)qb)[j];
    else if (j < 512) ((float4*)(biasq + 1024))[j-256] = ((const float4*)kb)[j-256];
    else if (j < 768) ((float4*)(biasq + 2048))[j-512] = ((const float4*)vbs)[j-512];
    else              ((float4*)biaso)[j-768]          = ((const float4*)ob)[j-768];
  }
}

// ---------------- NT GEMM: C[m,n] = sum_k A[m,k]*B[n,k] + bias[n] ----------------
// 128x128 tile, BK=32, 4 waves each 64x64 (4x4 of 16x16x32 MFMA). Ping-pong LDS
// staging, one barrier per K-iter (DMA for t+1 issued after barrier t).
// mode 0: scatter to q/k/v bf16 (h,s,hd).  mode 1: f32 row-major out.
__global__ __launch_bounds__(256) void gemm_nt(
    const unsigned short* __restrict__ A, const unsigned short* __restrict__ B,
    const float* __restrict__ bias, float* __restrict__ outF,
    unsigned short* __restrict__ dq, unsigned short* __restrict__ dk,
    unsigned short* __restrict__ dv, int M, int N, int K, int mode) {
  __shared__ alignas(16) unsigned short sA[2][128 * 32];
  __shared__ alignas(16) unsigned short sB[2][128 * 32];
  const int tid = threadIdx.x;
  const int lane = tid & 63, wave = tid >> 6;
  const int ln = lane & 15, quad = lane >> 4;
  const int bm = blockIdx.x * 128, bn = blockIdx.y * 128;
  const int wr = (wave >> 1) * 64, wc = (wave & 1) * 64;

  f32x4 acc[4][4];
#pragma unroll
  for (int i = 0; i < 4; ++i)
#pragma unroll
    for (int j = 0; j < 4; ++j) acc[i][j] = fzero4();

  // preload K-tile 0 into buffer 0
#pragma unroll
  for (int i = 0; i < 2; ++i) {
    int o = (i * 256 + tid) * 16;
    int e = o >> 1;
    int row = e >> 5, col = e & 31;
    gload16(A + (size_t)(bm + row) * K + col, (char*)sA[0] + o);
    gload16(B + (size_t)(bn + row) * K + col, (char*)sB[0] + o);
  }

  int buf = 0;
  for (int k0 = 0; k0 < K; k0 += 32, buf ^= 1) {
    __syncthreads();  // drains DMA for current buf; guards other buf vs old readers
    if (k0 + 32 < K) {
#pragma unroll
      for (int i = 0; i < 2; ++i) {
        int o = (i * 256 + tid) * 16;
        int e = o >> 1;
        int row = e >> 5, col = e & 31;
        gload16(A + (size_t)(bm + row) * K + k0 + 32 + col, (char*)sA[buf ^ 1] + o);
        gload16(B + (size_t)(bn + row) * K + k0 + 32 + col, (char*)sB[buf ^ 1] + o);
      }
    }
    bf16x8 af[4], bfr[4];
#pragma unroll
    for (int i = 0; i < 4; ++i) {
      af[i]  = *(const bf16x8*)&sA[buf][(wr + i * 16 + ln) * 32 + quad * 8];
      bfr[i] = *(const bf16x8*)&sB[buf][(wc + i * 16 + ln) * 32 + quad * 8];
    }
#pragma unroll
    for (int i = 0; i < 4; ++i)
#pragma unroll
      for (int j = 0; j < 4; ++j)
        acc[i][j] = __builtin_amdgcn_mfma_f32_16x16x32_bf16(af[i], bfr[j], acc[i][j], 0, 0, 0);
  }

  if (mode == 1) {
#pragma unroll
    for (int i = 0; i < 4; ++i)
#pragma unroll
      for (int j = 0; j < 4; ++j) {
        int n = bn + wc + j * 16 + ln;
        float bi = bias[n];
#pragma unroll
        for (int r = 0; r < 4; ++r) {
          int m = bm + wr + i * 16 + quad * 4 + r;
          outF[(size_t)m * N + n] = acc[i][j][r] + bi;
        }
      }
  } else {
    const int bufi = bn >> 10;
    unsigned short* const base = bufi == 0 ? dq : (bufi == 1 ? dk : dv);
    const int hq = ((bn & 1023) + wc) >> 6;  // head index, wave-uniform
#pragma unroll
    for (int i = 0; i < 4; ++i)
#pragma unroll
      for (int j = 0; j < 4; ++j) {
        int n = bn + wc + j * 16 + ln;
        float bi = bias[n];
        int hd = j * 16 + ln;
#pragma unroll
        for (int r = 0; r < 4; ++r) {
          int m = bm + wr + i * 16 + quad * 4 + r;
          base[((size_t)(hq * S_LEN + m)) * HD + hd] = f2b(acc[i][j][r] + bi);
        }
      }
  }
}

// ---------------- RoPE in-place on q,k (h,s,hd); q pre-scaled by 0.125*log2e ------
__global__ void rope_kernel(unsigned short* __restrict__ q, unsigned short* __restrict__ k,
                            const float* __restrict__ fc, const float* __restrict__ fs) {
  int idx = blockIdx.x * 256 + threadIdx.x;  // 2 * 16*4096*8
  const int P = NH * S_LEN * 8;
  bool isq = idx < P;
  unsigned short* t = isq ? q : k;
  int i = isq ? idx : idx - P;
  int g = i & 7;
  int s = (i >> 3) & 4095;
  int h = i >> 15;
  const float scale = isq ? 0.180336880f : 1.0f;  // (1/8)*log2(e) folded into q
  float4 c4 = *(const float4*)&fc[s * 32 + g * 4];
  float4 s4 = *(const float4*)&fs[s * 32 + g * 4];
  uint4* p = (uint4*)&t[((size_t)(h * S_LEN + s)) * HD + g * 8];
  uint4 pv = *p;
  auto rot = [&](unsigned int w, float c, float sn) -> unsigned int {
    float x0 = b2f((unsigned short)(w & 0xffffu));
    float x1 = b2f((unsigned short)(w >> 16));
    float o0 = (x0 * c - x1 * sn) * scale;
    float o1 = (x0 * sn + x1 * c) * scale;
    return (unsigned int)f2b(o0) | ((unsigned int)f2b(o1) << 16);
  };
  pv.x = rot(pv.x, c4.x, s4.x);
  pv.y = rot(pv.y, c4.y, s4.y);
  pv.z = rot(pv.z, c4.z, s4.z);
  pv.w = rot(pv.w, c4.w, s4.w);
  *p = pv;
}

// ---------------- V transpose: (h,s,hd) -> (h,hd,s), vectorized both global sides --
__global__ void transpose_v(const unsigned short* __restrict__ v, unsigned short* __restrict__ vt) {
  __shared__ unsigned short t[64][72];  // row stride 144B (multiple of 16) -> aligned b128
  const int h = blockIdx.y;
  const int s0 = blockIdx.x * 64;
  const int tid = threadIdx.x;
  const int r = tid >> 2, c0 = (tid & 3) * 16;
  const uint4* src = (const uint4*)(v + ((size_t)h * S_LEN + s0 + r) * HD + c0);
  uint4 a = src[0], b = src[1];
  *(uint4*)&t[r][c0] = a;
  *(uint4*)&t[r][c0 + 8] = b;
  __syncthreads();
  union { unsigned short u[16]; uint4 q[2]; } o;
#pragma unroll
  for (int j = 0; j < 16; ++j) o.u[j] = t[c0 + j][r];
  uint4* dst = (uint4*)(vt + ((size_t)h * HD + r) * S_LEN + s0 + c0);
  dst[0] = o.q[0];
  dst[1] = o.q[1];
}

// ---------------- LDS swizzled 16B reads (chunk XOR to spread banks) ----------------
__device__ __forceinline__ bf16x8 lds_swzK(const unsigned short* s, int row, int chunk) {
  int byte = row * 128 + ((chunk ^ ((row >> 2) & 7)) << 4);
  return *(const bf16x8*)((const char*)s + byte);
}
__device__ __forceinline__ bf16x8 lds_swzV(const unsigned short* s, int row, int chunk) {
  int byte = row * 128 + ((chunk ^ (row & 7)) << 4);
  return *(const bf16x8*)((const char*)s + byte);
}

// ---------------- Flash attention, causal, exp2 softmax (no running max) ----------
// 2-wave blocks (128 thr), 64 q-rows per block, 32 rows/wave (mt=2):
// K/V LDS reads are per-wave and row-count-independent, so halving waves halves
// them (R6's amortization) while the grid stays at 1024 blocks (R5's parallelism —
// R6's 512-block grid was the regression: 2 blocks/CU grid-limited, occ 12.5%).
// Per-step LDS ~704 cyc vs R5's ~1470; step count unchanged (130/CU balanced).
// LDS 25.6 KB -> 6 blocks/CU capacity. Complementary qb swizzle as R5.
// Score col ln of tile t <-> kv row 4*ln+t; mask only diagonal-straddling tiles;
// l via MFMA-with-ones (C-layout like O).
__global__ __launch_bounds__(128, 3) void flash_kernel(
    const unsigned short* __restrict__ qg, const unsigned short* __restrict__ kg,
    const unsigned short* __restrict__ vtg, unsigned short* __restrict__ attn) {
  __shared__ alignas(16) unsigned short sK[64 * 64];
  __shared__ alignas(16) unsigned short sV[64 * 64];
  __shared__ alignas(16) unsigned short sP[2 * 32 * 72];  // per-wave 32x64, stride 72

  const int tid = threadIdx.x;
  const int lane = tid & 63, wave = tid >> 6;  // wave in {0,1}
  const int ln = lane & 15, quad = lane >> 4;
  const int h = blockIdx.y;
  const int qb = ((h >> 2) & 1) ? (int)blockIdx.x : 63 - (int)blockIdx.x;
  const int q0 = qb * 64;
  const int qrow = q0 + wave * 32;

  const unsigned short* qh = qg + (size_t)h * (S_LEN * HD);
  const unsigned short* kh = kg + (size_t)h * (S_LEN * HD);
  const unsigned short* vh = vtg + (size_t)h * (HD * S_LEN);

  // Q fragments (A-layout: m=ln, k=quad*8+j), 32 rows/wave
  bf16x8 qf[2][2];
#pragma unroll
  for (int mt = 0; mt < 2; ++mt)
#pragma unroll
    for (int ks = 0; ks < 2; ++ks)
      qf[mt][ks] = *(const bf16x8*)(qh + (size_t)(qrow + mt * 16 + ln) * HD + ks * 32 + quad * 8);

  f32x4 o_acc[2][4];
  f32x4 l_acc[2];
#pragma unroll
  for (int mt = 0; mt < 2; ++mt) {
    l_acc[mt] = fzero4();
#pragma unroll
    for (int t = 0; t < 4; ++t) o_acc[mt][t] = fzero4();
  }
  bf16x8 ones;
#pragma unroll
  for (int j = 0; j < 8; ++j) ones[j] = (short)0x3F80;  // bf16 1.0

  unsigned short* pw = &sP[wave * (32 * 72)];
  const int nkv = qb + 1;

  for (int kt = 0; kt < nkv; ++kt) {
    const int kv0 = kt * 64;
    __syncthreads();  // protect sK/sV from previous iteration's readers
#pragma unroll
    for (int i = 0; i < 4; ++i) {
      int ob = (i * 128 + tid) * 16;
      int row = ob >> 7;
      int ch = (ob >> 4) & 7;
      gload16(kh + (size_t)(kv0 + row) * HD + ((ch ^ ((row >> 2) & 7)) << 3), (char*)sK + ob);
      gload16(vh + (size_t)row * S_LEN + kv0 + ((ch ^ (row & 7)) << 3), (char*)sV + ob);
    }
    __syncthreads();

    // S = Q K^T (tile t col ln <-> kv row 4*ln+t)
    f32x4 sc[2][4];
#pragma unroll
    for (int mt = 0; mt < 2; ++mt)
#pragma unroll
      for (int t = 0; t < 4; ++t) sc[mt][t] = fzero4();
#pragma unroll
    for (int t = 0; t < 4; ++t) {
      int krow = ln * 4 + t;
      bf16x8 kb0 = lds_swzK(sK, krow, quad);
      bf16x8 kb1 = lds_swzK(sK, krow, 4 + quad);
#pragma unroll
      for (int mt = 0; mt < 2; ++mt) {
        sc[mt][t] = __builtin_amdgcn_mfma_f32_16x16x32_bf16(qf[mt][0], kb0, sc[mt][t], 0, 0, 0);
        sc[mt][t] = __builtin_amdgcn_mfma_f32_16x16x32_bf16(qf[mt][1], kb1, sc[mt][t], 0, 0, 0);
      }
    }

    // p = exp2(s); mask only when tile straddles this wave's rows; truncation pack
    if (kv0 + 63 > qrow) {
#pragma unroll
      for (int mt = 0; mt < 2; ++mt)
#pragma unroll
        for (int r = 0; r < 4; ++r) {
          int row = qrow + mt * 16 + quad * 4 + r;
          int colb = kv0 + ln * 4;
          float p0 = (colb + 0 <= row) ? __builtin_amdgcn_exp2f(sc[mt][0][r]) : 0.0f;
          float p1 = (colb + 1 <= row) ? __builtin_amdgcn_exp2f(sc[mt][1][r]) : 0.0f;
          float p2 = (colb + 2 <= row) ? __builtin_amdgcn_exp2f(sc[mt][2][r]) : 0.0f;
          float p3 = (colb + 3 <= row) ? __builtin_amdgcn_exp2f(sc[mt][3][r]) : 0.0f;
          *(uint2*)&pw[(mt * 16 + quad * 4 + r) * 72 + ln * 4] =
              make_uint2(pk2t(p0, p1), pk2t(p2, p3));
        }
    } else {
#pragma unroll
      for (int mt = 0; mt < 2; ++mt)
#pragma unroll
        for (int r = 0; r < 4; ++r) {
          float p0 = __builtin_amdgcn_exp2f(sc[mt][0][r]);
          float p1 = __builtin_amdgcn_exp2f(sc[mt][1][r]);
          float p2 = __builtin_amdgcn_exp2f(sc[mt][2][r]);
          float p3 = __builtin_amdgcn_exp2f(sc[mt][3][r]);
          *(uint2*)&pw[(mt * 16 + quad * 4 + r) * 72 + ln * 4] =
              make_uint2(pk2t(p0, p1), pk2t(p2, p3));
        }
    }

    // P fragments (A-layout), per-wave region -> no barrier needed
    bf16x8 pa[2][2];
#pragma unroll
    for (int mt = 0; mt < 2; ++mt) {
      pa[mt][0] = *(const bf16x8*)&pw[(mt * 16 + ln) * 72 + quad * 8];
      pa[mt][1] = *(const bf16x8*)&pw[(mt * 16 + ln) * 72 + 32 + quad * 8];
    }

    // l += P @ ones
#pragma unroll
    for (int mt = 0; mt < 2; ++mt) {
      l_acc[mt] = __builtin_amdgcn_mfma_f32_16x16x32_bf16(pa[mt][0], ones, l_acc[mt], 0, 0, 0);
      l_acc[mt] = __builtin_amdgcn_mfma_f32_16x16x32_bf16(pa[mt][1], ones, l_acc[mt], 0, 0, 0);
    }

    // O += P @ V
#pragma unroll
    for (int t = 0; t < 4; ++t) {
      int vrow = t * 16 + ln;
      bf16x8 vb0 = lds_swzV(sV, vrow, quad);
      bf16x8 vb1 = lds_swzV(sV, vrow, 4 + quad);
#pragma unroll
      for (int mt = 0; mt < 2; ++mt) {
        o_acc[mt][t] = __builtin_amdgcn_mfma_f32_16x16x32_bf16(pa[mt][0], vb0, o_acc[mt][t], 0, 0, 0);
        o_acc[mt][t] = __builtin_amdgcn_mfma_f32_16x16x32_bf16(pa[mt][1], vb1, o_acc[mt][t], 0, 0, 0);
      }
    }
  }

  // epilogue: attn[s, h*64+hd] = O/l (bf16)
#pragma unroll
  for (int mt = 0; mt < 2; ++mt) {
    float inv[4];
#pragma unroll
    for (int r = 0; r < 4; ++r) inv[r] = 1.0f / l_acc[mt][r];
#pragma unroll
    for (int t = 0; t < 4; ++t)
#pragma unroll
      for (int r = 0; r < 4; ++r) {
        int row = qrow + mt * 16 + quad * 4 + r;
        attn[(size_t)row * DIM + h * HD + t * 16 + ln] = f2b(o_acc[mt][t][r] * inv[r]);
      }
  }
}

extern "C" void kernel_launch(void* const* d_in, const int* in_sizes, int n_in,
                              void* d_out, int out_size, void* d_ws, size_t ws_size,
                              hipStream_t stream) {
  const float* x    = (const float*)d_in[0];
  const float* fc   = (const float*)d_in[2];
  const float* fs   = (const float*)d_in[3];
  const float* wqw  = (const float*)d_in[5];
  const float* wqb  = (const float*)d_in[6];
  const float* wkw  = (const float*)d_in[7];
  const float* wkb  = (const float*)d_in[8];
  const float* wvw  = (const float*)d_in[9];
  const float* wvb  = (const float*)d_in[10];
  const float* wow  = (const float*)d_in[11];
  const float* wobf = (const float*)d_in[12];
  float* out = (float*)d_out;

  char* ws = (char*)d_ws;
  const size_t MB = (size_t)1 << 20;
  unsigned short* xb    = (unsigned short*)(ws + 0);
  unsigned short* wqkvb = (unsigned short*)(ws + 8 * MB);
  unsigned short* wobb  = (unsigned short*)(ws + 16 * MB);
  float* biasq = (float*)(ws + 18 * MB);
  float* biaso = (float*)(ws + 18 * MB + 65536);
  unsigned short* qb_ = (unsigned short*)(ws + 19 * MB);
  unsigned short* kb_ = (unsigned short*)(ws + 27 * MB);
  unsigned short* vb_ = (unsigned short*)(ws + 35 * MB);
  unsigned short* vt  = (unsigned short*)(ws + 8 * MB);  // aliases wqkvb (dead after QKV GEMM)
  unsigned short* attn = (unsigned short*)(ws + 0);      // aliases xb (dead after QKV GEMM)

  cvt_all<<<8196, 256, 0, stream>>>(x, wqw, wkw, wvw, wow, wqb, wkb, wvb, wobf,
                                    xb, wqkvb, wobb, biasq, biaso);
  gemm_nt<<<dim3(32, 24), 256, 0, stream>>>(xb, wqkvb, biasq, nullptr, qb_, kb_, vb_,
                                            4096, 3072, 1024, 0);
  rope_kernel<<<4096, 256, 0, stream>>>(qb_, kb_, fc, fs);
  transpose_v<<<dim3(64, 16), 256, 0, stream>>>(vb_, vt);
  flash_kernel<<<dim3(64, 16), 128, 0, stream>>>(qb_, kb_, vt, attn);
  gemm_nt<<<dim3(32, 8), 256, 0, stream>>>(attn, wobb, biaso, out, nullptr, nullptr, nullptr,
                                           4096, 1024, 1024, 1);
}

// Round 8
// 283.343 us; speedup vs baseline: 1.0502x; 1.0269x over previous
//
#include <hip/hip_runtime.h>

// AttentionLoRA: B=1, S=4096, D=1024, H=16, HD=64.
// Pipeline (4 kernels):
//   cvt_all (f32->bf16 + bias pack)
//   gemm1: QKV NT-GEMM, epilogue fuses RoPE (q/k, shfl_xor partner) and V-transpose
//          (per-wave LDS scratch -> vT (h,hd,s)) ; q pre-scaled by 0.125*log2e
//   flash: causal, exp2 softmax, K+V DMA-staged; each block runs the q-tile PAIR
//          (x, 63-x) sequentially -> uniform 65 kv-steps/block, constant occupancy
//   gemm2: out-proj, f32 out.

#define S_LEN 4096
#define DIM   1024
#define NH    16
#define HD    64

typedef __attribute__((ext_vector_type(8))) short bf16x8;   // 8 bf16 = 4 VGPRs
typedef __attribute__((ext_vector_type(4))) float f32x4;

__device__ __forceinline__ unsigned short f2b(float f) {
  union { float f; unsigned int u; } v; v.f = f;
  unsigned int r = (v.u + 0x7fffu + ((v.u >> 16) & 1u)) >> 16;  // RNE
  return (unsigned short)r;
}
__device__ __forceinline__ float b2f(unsigned short h) {
  union { unsigned int u; float f; } v; v.u = ((unsigned int)h) << 16;
  return v.f;
}
// pack two f32 -> two bf16 by truncation (p in [0,1]; <=1ulp)
__device__ __forceinline__ unsigned int pk2t(float a, float b) {
  union { float f; unsigned int u; } x, y; x.f = a; y.f = b;
  return (x.u >> 16) | (y.u & 0xffff0000u);
}
__device__ __forceinline__ void gload16(const void* g, void* l) {
  __builtin_amdgcn_global_load_lds(
      (const __attribute__((address_space(1))) unsigned int*)g,
      (__attribute__((address_space(3))) unsigned int*)l, 16, 0, 0);
}
__device__ __forceinline__ f32x4 fzero4() { f32x4 z = {0.f, 0.f, 0.f, 0.f}; return z; }

// ---------------- fused f32->bf16 convert (x, wq, wk, wv, wo) + bias pack ----------
__global__ void cvt_all(const float* __restrict__ x, const float* __restrict__ wq,
                        const float* __restrict__ wk, const float* __restrict__ wv,
                        const float* __restrict__ wo, const float* __restrict__ qb,
                        const float* __restrict__ kb, const float* __restrict__ vbs,
                        const float* __restrict__ ob, unsigned short* __restrict__ xb,
                        unsigned short* __restrict__ wqkvb, unsigned short* __restrict__ wobb,
                        float* __restrict__ biasq, float* __restrict__ biaso) {
  int i = blockIdx.x * 256 + threadIdx.x;  // float4 index
  if (i < 2097152) {
    const float* src; unsigned short* dst; int off;
    if (i < 1048576)      { src = x;  dst = xb;              off = i; }
    else if (i < 1310720) { src = wq; dst = wqkvb;           off = i - 1048576; }
    else if (i < 1572864) { src = wk; dst = wqkvb + 1048576; off = i - 1310720; }
    else if (i < 1835008) { src = wv; dst = wqkvb + 2097152; off = i - 1572864; }
    else                  { src = wo; dst = wobb;            off = i - 1835008; }
    float4 v = ((const float4*)src)[off];
    unsigned int lo = (unsigned int)f2b(v.x) | ((unsigned int)f2b(v.y) << 16);
    unsigned int hi = (unsigned int)f2b(v.z) | ((unsigned int)f2b(v.w) << 16);
    ((uint2*)dst)[off] = make_uint2(lo, hi);
  } else if (i < 2097152 + 1024) {
    int j = i - 2097152;
    if (j < 256)      ((float4*)biasq)[j]              = ((const float4*)qb)[j];
    else if (j < 512) ((float4*)(biasq + 1024))[j-256] = ((const float4*)kb)[j-256];
    else if (j < 768) ((float4*)(biasq + 2048))[j-512] = ((const float4*)vbs)[j-512];
    else              ((float4*)biaso)[j-768]          = ((const float4*)ob)[j-768];
  }
}

// ---------------- NT GEMM: C[m,n] = sum_k A[m,k]*B[n,k] + bias[n] ----------------
// 128x128 tile, BK=32, 4 waves each 64x64 (4x4 of 16x16x32 MFMA). Ping-pong LDS
// staging, one barrier per K-iter. mode 1: f32 row-major out.
// mode 0 (QKV): q/k epilogue fuses RoPE (partner via shfl_xor(1); q scaled by
// 0.125*log2e on f32 before rounding); v epilogue writes vT (h,hd,s) via per-wave
// 8KB LDS scratch (dead sA/sB), XOR-swizzled 16B chunks, coalesced row stores.
__global__ __launch_bounds__(256) void gemm_nt(
    const unsigned short* __restrict__ A, const unsigned short* __restrict__ B,
    const float* __restrict__ bias, float* __restrict__ outF,
    unsigned short* __restrict__ dq, unsigned short* __restrict__ dk,
    unsigned short* __restrict__ vtout, const float* __restrict__ fc,
    const float* __restrict__ fs, int M, int N, int K, int mode) {
  __shared__ alignas(16) unsigned short sA[2][128 * 32];
  __shared__ alignas(16) unsigned short sB[2][128 * 32];
  const int tid = threadIdx.x;
  const int lane = tid & 63, wave = tid >> 6;
  const int ln = lane & 15, quad = lane >> 4;
  const int bm = blockIdx.x * 128, bn = blockIdx.y * 128;
  const int wr = (wave >> 1) * 64, wc = (wave & 1) * 64;

  f32x4 acc[4][4];
#pragma unroll
  for (int i = 0; i < 4; ++i)
#pragma unroll
    for (int j = 0; j < 4; ++j) acc[i][j] = fzero4();

  // preload K-tile 0 into buffer 0
#pragma unroll
  for (int i = 0; i < 2; ++i) {
    int o = (i * 256 + tid) * 16;
    int e = o >> 1;
    int row = e >> 5, col = e & 31;
    gload16(A + (size_t)(bm + row) * K + col, (char*)sA[0] + o);
    gload16(B + (size_t)(bn + row) * K + col, (char*)sB[0] + o);
  }

  int buf = 0;
  for (int k0 = 0; k0 < K; k0 += 32, buf ^= 1) {
    __syncthreads();  // drains DMA for current buf; guards other buf vs old readers
    if (k0 + 32 < K) {
#pragma unroll
      for (int i = 0; i < 2; ++i) {
        int o = (i * 256 + tid) * 16;
        int e = o >> 1;
        int row = e >> 5, col = e & 31;
        gload16(A + (size_t)(bm + row) * K + k0 + 32 + col, (char*)sA[buf ^ 1] + o);
        gload16(B + (size_t)(bn + row) * K + k0 + 32 + col, (char*)sB[buf ^ 1] + o);
      }
    }
    bf16x8 af[4], bfr[4];
#pragma unroll
    for (int i = 0; i < 4; ++i) {
      af[i]  = *(const bf16x8*)&sA[buf][(wr + i * 16 + ln) * 32 + quad * 8];
      bfr[i] = *(const bf16x8*)&sB[buf][(wc + i * 16 + ln) * 32 + quad * 8];
    }
#pragma unroll
    for (int i = 0; i < 4; ++i)
#pragma unroll
      for (int j = 0; j < 4; ++j)
        acc[i][j] = __builtin_amdgcn_mfma_f32_16x16x32_bf16(af[i], bfr[j], acc[i][j], 0, 0, 0);
  }

  if (mode == 1) {
#pragma unroll
    for (int i = 0; i < 4; ++i)
#pragma unroll
      for (int j = 0; j < 4; ++j) {
        int n = bn + wc + j * 16 + ln;
        float bi = bias[n];
#pragma unroll
        for (int r = 0; r < 4; ++r) {
          int m = bm + wr + i * 16 + quad * 4 + r;
          outF[(size_t)m * N + n] = acc[i][j][r] + bi;
        }
      }
  } else {
    const int bufi = bn >> 10;                  // 0:q 1:k 2:v (block-uniform)
    const int hq = ((bn & 1023) + wc) >> 6;     // head, wave-uniform
    if (bufi < 2) {
      // ---- q/k with fused RoPE ----
      unsigned short* const base = bufi == 0 ? dq : dk;
      const float qsc = bufi == 0 ? 0.180336880f : 1.0f;  // (1/8)*log2(e) for q
#pragma unroll
      for (int i = 0; i < 4; ++i)
#pragma unroll
        for (int j = 0; j < 4; ++j) {
          int n = bn + wc + j * 16 + ln;
          float bi = bias[n];
          int hd = j * 16 + ln;
          int pi = hd >> 1;
          bool evn = (ln & 1) == 0;
#pragma unroll
          for (int r = 0; r < 4; ++r) {
            int m = bm + wr + i * 16 + quad * 4 + r;
            float val = acc[i][j][r] + bi;
            float par = __shfl_xor(val, 1);     // partner of the (2p,2p+1) pair
            float c = fc[m * 32 + pi], sn = fs[m * 32 + pi];
            float o = evn ? (val * c - par * sn) : (par * sn + val * c);
            base[((size_t)(hq * S_LEN + m)) * HD + hd] = f2b(o * qsc);
          }
        }
    } else {
      // ---- v: write transposed (h,hd,s) via per-wave LDS scratch ----
      __syncthreads();  // all waves done reading sA/sB (K-loop) before reuse
      unsigned short* scr =
          (wave < 2 ? (unsigned short*)sA : (unsigned short*)sB) + (wave & 1) * 4096;
#pragma unroll
      for (int i = 0; i < 4; ++i)
#pragma unroll
        for (int j = 0; j < 4; ++j) {
          int n = bn + wc + j * 16 + ln;
          float bi = bias[n];
          int hd = j * 16 + ln;
#pragma unroll
          for (int r = 0; r < 4; ++r) {
            int sl = i * 16 + quad * 4 + r;     // local s index 0..63
            int byte = hd * 128 + ((((sl >> 3) ^ (hd & 7)) << 4)) + (sl & 7) * 2;
            *(unsigned short*)((char*)scr + byte) = f2b(acc[i][j][r] + bi);
          }
        }
      // wave-private region: same-wave DS ordering makes the readback safe
#pragma unroll
      for (int pass = 0; pass < 4; ++pass) {
        int row = pass * 16 + ln;               // hd row of vT
        uint4 d0 = *(uint4*)((char*)scr + row * 128 + (((quad * 2) ^ (row & 7)) << 4));
        uint4 d1 = *(uint4*)((char*)scr + row * 128 + (((quad * 2 + 1) ^ (row & 7)) << 4));
        uint4* dst = (uint4*)(vtout + ((size_t)(hq * HD + row)) * S_LEN + bm + wr + quad * 16);
        dst[0] = d0;
        dst[1] = d1;
      }
    }
  }
}

// ---------------- LDS swizzled 16B reads (chunk XOR to spread banks) ----------------
__device__ __forceinline__ bf16x8 lds_swzK(const unsigned short* s, int row, int chunk) {
  int byte = row * 128 + ((chunk ^ ((row >> 2) & 7)) << 4);
  return *(const bf16x8*)((const char*)s + byte);
}
__device__ __forceinline__ bf16x8 lds_swzV(const unsigned short* s, int row, int chunk) {
  int byte = row * 128 + ((chunk ^ (row & 7)) << 4);
  return *(const bf16x8*)((const char*)s + byte);
}

// ---------------- Flash attention, causal, exp2 softmax (no running max) ----------
// R5 body (K+V DMA-staged, 4 waves x 16 q-rows — the measured-fastest) wrapped in a
// q-tile PAIR loop: block handles tiles x and 63-x sequentially -> exactly 65
// kv-steps per block. All 512 blocks uniform => 2 blocks/CU, 16 waves/CU constant
// (fixes R7's drained-tail occupancy 11.6%: short blocks finished early and could
// not be refilled since the whole grid is resident).
__global__ __launch_bounds__(256, 4) void flash_kernel(
    const unsigned short* __restrict__ qg, const unsigned short* __restrict__ kg,
    const unsigned short* __restrict__ vtg, unsigned short* __restrict__ attn) {
  __shared__ alignas(16) unsigned short sK[64 * 64];
  __shared__ alignas(16) unsigned short sV[64 * 64];
  __shared__ alignas(16) unsigned short sP[4 * 16 * 72];  // per-wave 16x64, stride 72

  const int tid = threadIdx.x;
  const int lane = tid & 63, wave = tid >> 6;
  const int ln = lane & 15, quad = lane >> 4;
  const int h = blockIdx.y;

  const unsigned short* qh = qg + (size_t)h * (S_LEN * HD);
  const unsigned short* kh = kg + (size_t)h * (S_LEN * HD);
  const unsigned short* vh = vtg + (size_t)h * (HD * S_LEN);

  bf16x8 ones;
#pragma unroll
  for (int j = 0; j < 8; ++j) ones[j] = (short)0x3F80;  // bf16 1.0
  unsigned short* pw = &sP[wave * (16 * 72)];

  for (int p = 0; p < 2; ++p) {
    const int qb = p == 0 ? (int)blockIdx.x : 63 - (int)blockIdx.x;
    const int q0 = qb * 64;
    const int qrow = q0 + wave * 16;

    bf16x8 qf[2];
    qf[0] = *(const bf16x8*)(qh + (size_t)(qrow + ln) * HD + quad * 8);
    qf[1] = *(const bf16x8*)(qh + (size_t)(qrow + ln) * HD + 32 + quad * 8);

    f32x4 o_acc[4];
    f32x4 l_acc = fzero4();
#pragma unroll
    for (int t = 0; t < 4; ++t) o_acc[t] = fzero4();

    const int nkv = qb + 1;
    for (int kt = 0; kt < nkv; ++kt) {
      const int kv0 = kt * 64;
      __syncthreads();  // protect sK/sV from previous iteration's readers
#pragma unroll
      for (int i = 0; i < 2; ++i) {
        int ob = (i * 256 + tid) * 16;
        int row = ob >> 7;
        int ch = (ob >> 4) & 7;
        gload16(kh + (size_t)(kv0 + row) * HD + ((ch ^ ((row >> 2) & 7)) << 3), (char*)sK + ob);
        gload16(vh + (size_t)row * S_LEN + kv0 + ((ch ^ (row & 7)) << 3), (char*)sV + ob);
      }
      __syncthreads();

      // S = Q K^T (tile t col ln <-> kv row 4*ln+t)
      f32x4 sc[4];
#pragma unroll
      for (int t = 0; t < 4; ++t) sc[t] = fzero4();
#pragma unroll
      for (int t = 0; t < 4; ++t) {
        int krow = ln * 4 + t;
        bf16x8 kb0 = lds_swzK(sK, krow, quad);
        bf16x8 kb1 = lds_swzK(sK, krow, 4 + quad);
        sc[t] = __builtin_amdgcn_mfma_f32_16x16x32_bf16(qf[0], kb0, sc[t], 0, 0, 0);
        sc[t] = __builtin_amdgcn_mfma_f32_16x16x32_bf16(qf[1], kb1, sc[t], 0, 0, 0);
      }

      // p = exp2(s); mask only on diagonal tile; truncation pack; b64 LDS writes
      if (kt == nkv - 1) {
#pragma unroll
        for (int r = 0; r < 4; ++r) {
          int row = qrow + quad * 4 + r;
          int colb = kv0 + ln * 4;
          float p0 = (colb + 0 <= row) ? __builtin_amdgcn_exp2f(sc[0][r]) : 0.0f;
          float p1 = (colb + 1 <= row) ? __builtin_amdgcn_exp2f(sc[1][r]) : 0.0f;
          float p2 = (colb + 2 <= row) ? __builtin_amdgcn_exp2f(sc[2][r]) : 0.0f;
          float p3 = (colb + 3 <= row) ? __builtin_amdgcn_exp2f(sc[3][r]) : 0.0f;
          *(uint2*)&pw[(quad * 4 + r) * 72 + ln * 4] = make_uint2(pk2t(p0, p1), pk2t(p2, p3));
        }
      } else {
#pragma unroll
        for (int r = 0; r < 4; ++r) {
          float p0 = __builtin_amdgcn_exp2f(sc[0][r]);
          float p1 = __builtin_amdgcn_exp2f(sc[1][r]);
          float p2 = __builtin_amdgcn_exp2f(sc[2][r]);
          float p3 = __builtin_amdgcn_exp2f(sc[3][r]);
          *(uint2*)&pw[(quad * 4 + r) * 72 + ln * 4] = make_uint2(pk2t(p0, p1), pk2t(p2, p3));
        }
      }

      // P fragments (A-layout), per-wave region -> no barrier needed
      bf16x8 pa0 = *(const bf16x8*)&pw[ln * 72 + quad * 8];
      bf16x8 pa1 = *(const bf16x8*)&pw[ln * 72 + 32 + quad * 8];

      // l += P @ ones
      l_acc = __builtin_amdgcn_mfma_f32_16x16x32_bf16(pa0, ones, l_acc, 0, 0, 0);
      l_acc = __builtin_amdgcn_mfma_f32_16x16x32_bf16(pa1, ones, l_acc, 0, 0, 0);

      // O += P @ V
#pragma unroll
      for (int t = 0; t < 4; ++t) {
        int vrow = t * 16 + ln;
        bf16x8 vb0 = lds_swzV(sV, vrow, quad);
        bf16x8 vb1 = lds_swzV(sV, vrow, 4 + quad);
        o_acc[t] = __builtin_amdgcn_mfma_f32_16x16x32_bf16(pa0, vb0, o_acc[t], 0, 0, 0);
        o_acc[t] = __builtin_amdgcn_mfma_f32_16x16x32_bf16(pa1, vb1, o_acc[t], 0, 0, 0);
      }
    }

    // epilogue for this tile: attn[s, h*64+hd] = O/l (bf16)
    float inv[4];
#pragma unroll
    for (int r = 0; r < 4; ++r) inv[r] = 1.0f / l_acc[r];
#pragma unroll
    for (int t = 0; t < 4; ++t)
#pragma unroll
      for (int r = 0; r < 4; ++r) {
        int row = qrow + quad * 4 + r;
        attn[(size_t)row * DIM + h * HD + t * 16 + ln] = f2b(o_acc[t][r] * inv[r]);
      }
  }
}

extern "C" void kernel_launch(void* const* d_in, const int* in_sizes, int n_in,
                              void* d_out, int out_size, void* d_ws, size_t ws_size,
                              hipStream_t stream) {
  const float* x    = (const float*)d_in[0];
  const float* fc   = (const float*)d_in[2];
  const float* fs   = (const float*)d_in[3];
  const float* wqw  = (const float*)d_in[5];
  const float* wqb  = (const float*)d_in[6];
  const float* wkw  = (const float*)d_in[7];
  const float* wkb  = (const float*)d_in[8];
  const float* wvw  = (const float*)d_in[9];
  const float* wvb  = (const float*)d_in[10];
  const float* wow  = (const float*)d_in[11];
  const float* wobf = (const float*)d_in[12];
  float* out = (float*)d_out;

  char* ws = (char*)d_ws;
  const size_t MB = (size_t)1 << 20;
  unsigned short* xb    = (unsigned short*)(ws + 0);
  unsigned short* wqkvb = (unsigned short*)(ws + 8 * MB);
  unsigned short* wobb  = (unsigned short*)(ws + 16 * MB);
  float* biasq = (float*)(ws + 18 * MB);
  float* biaso = (float*)(ws + 18 * MB + 65536);
  unsigned short* qb_ = (unsigned short*)(ws + 19 * MB);
  unsigned short* kb_ = (unsigned short*)(ws + 27 * MB);
  unsigned short* vt  = (unsigned short*)(ws + 35 * MB);  // vT written by gemm1
  unsigned short* attn = (unsigned short*)(ws + 0);       // aliases xb (dead after gemm1)

  cvt_all<<<8196, 256, 0, stream>>>(x, wqw, wkw, wvw, wow, wqb, wkb, wvb, wobf,
                                    xb, wqkvb, wobb, biasq, biaso);
  gemm_nt<<<dim3(32, 24), 256, 0, stream>>>(xb, wqkvb, biasq, nullptr, qb_, kb_, vt,
                                            fc, fs, 4096, 3072, 1024, 0);
  flash_kernel<<<dim3(32, 16), 256, 0, stream>>>(qb_, kb_, vt, attn);
  gemm_nt<<<dim3(32, 8), 256, 0, stream>>>(attn, wobb, biaso, out, nullptr, nullptr, nullptr,
                                           nullptr, nullptr, 4096, 1024, 1024, 1);
}

// Round 9
// 267.744 us; speedup vs baseline: 1.1114x; 1.0583x over previous
//
#include <hip/hip_runtime.h>

// AttentionLoRA: B=1, S=4096, D=1024, H=16, HD=64.
// Pipeline (4 kernels):
//   cvt_all (f32->bf16 + bias pack)
//   gemm1: QKV NT-GEMM, epilogue fuses RoPE (q/k) and V-transpose -> vT (h,hd,s)
//   flash: causal, exp2 softmax; q-tile PAIR (x,63-x) per block (uniform 65 steps);
//          K+V ping-pong DMA staging (drain hidden behind compute); XCD-aware
//          swizzle (2 heads per XCD -> KV fits per-XCD L2)
//   gemm2: out-proj, 128x64 tiles (512 blocks, 2/CU), f32 out.

#define S_LEN 4096
#define DIM   1024
#define NH    16
#define HD    64

typedef __attribute__((ext_vector_type(8))) short bf16x8;   // 8 bf16 = 4 VGPRs
typedef __attribute__((ext_vector_type(4))) float f32x4;

__device__ __forceinline__ unsigned short f2b(float f) {
  union { float f; unsigned int u; } v; v.f = f;
  unsigned int r = (v.u + 0x7fffu + ((v.u >> 16) & 1u)) >> 16;  // RNE
  return (unsigned short)r;
}
__device__ __forceinline__ float b2f(unsigned short h) {
  union { unsigned int u; float f; } v; v.u = ((unsigned int)h) << 16;
  return v.f;
}
// pack two f32 -> two bf16 by truncation (p in [0,1]; <=1ulp)
__device__ __forceinline__ unsigned int pk2t(float a, float b) {
  union { float f; unsigned int u; } x, y; x.f = a; y.f = b;
  return (x.u >> 16) | (y.u & 0xffff0000u);
}
__device__ __forceinline__ void gload16(const void* g, void* l) {
  __builtin_amdgcn_global_load_lds(
      (const __attribute__((address_space(1))) unsigned int*)g,
      (__attribute__((address_space(3))) unsigned int*)l, 16, 0, 0);
}
__device__ __forceinline__ f32x4 fzero4() { f32x4 z = {0.f, 0.f, 0.f, 0.f}; return z; }

// ---------------- fused f32->bf16 convert (x, wq, wk, wv, wo) + bias pack ----------
__global__ void cvt_all(const float* __restrict__ x, const float* __restrict__ wq,
                        const float* __restrict__ wk, const float* __restrict__ wv,
                        const float* __restrict__ wo, const float* __restrict__ qb,
                        const float* __restrict__ kb, const float* __restrict__ vbs,
                        const float* __restrict__ ob, unsigned short* __restrict__ xb,
                        unsigned short* __restrict__ wqkvb, unsigned short* __restrict__ wobb,
                        float* __restrict__ biasq, float* __restrict__ biaso) {
  int i = blockIdx.x * 256 + threadIdx.x;  // float4 index
  if (i < 2097152) {
    const float* src; unsigned short* dst; int off;
    if (i < 1048576)      { src = x;  dst = xb;              off = i; }
    else if (i < 1310720) { src = wq; dst = wqkvb;           off = i - 1048576; }
    else if (i < 1572864) { src = wk; dst = wqkvb + 1048576; off = i - 1310720; }
    else if (i < 1835008) { src = wv; dst = wqkvb + 2097152; off = i - 1572864; }
    else                  { src = wo; dst = wobb;            off = i - 1835008; }
    float4 v = ((const float4*)src)[off];
    unsigned int lo = (unsigned int)f2b(v.x) | ((unsigned int)f2b(v.y) << 16);
    unsigned int hi = (unsigned int)f2b(v.z) | ((unsigned int)f2b(v.w) << 16);
    ((uint2*)dst)[off] = make_uint2(lo, hi);
  } else if (i < 2097152 + 1024) {
    int j = i - 2097152;
    if (j < 256)      ((float4*)biasq)[j]              = ((const float4*)qb)[j];
    else if (j < 512) ((float4*)(biasq + 1024))[j-256] = ((const float4*)kb)[j-256];
    else if (j < 768) ((float4*)(biasq + 2048))[j-512] = ((const float4*)vbs)[j-512];
    else              ((float4*)biaso)[j-768]          = ((const float4*)ob)[j-768];
  }
}

// ---------------- gemm1: QKV NT-GEMM with fused RoPE + V-transpose epilogue -------
// 128x128 tile, BK=32, 4 waves each 64x64. Ping-pong LDS staging, 1 barrier/K-iter.
__global__ __launch_bounds__(256) void gemm_qkv(
    const unsigned short* __restrict__ A, const unsigned short* __restrict__ B,
    const float* __restrict__ bias, unsigned short* __restrict__ dq,
    unsigned short* __restrict__ dk, unsigned short* __restrict__ vtout,
    const float* __restrict__ fc, const float* __restrict__ fs, int K) {
  __shared__ alignas(16) unsigned short sA[2][128 * 32];
  __shared__ alignas(16) unsigned short sB[2][128 * 32];
  const int tid = threadIdx.x;
  const int lane = tid & 63, wave = tid >> 6;
  const int ln = lane & 15, quad = lane >> 4;
  const int bm = blockIdx.x * 128, bn = blockIdx.y * 128;
  const int wr = (wave >> 1) * 64, wc = (wave & 1) * 64;

  f32x4 acc[4][4];
#pragma unroll
  for (int i = 0; i < 4; ++i)
#pragma unroll
    for (int j = 0; j < 4; ++j) acc[i][j] = fzero4();

#pragma unroll
  for (int i = 0; i < 2; ++i) {
    int o = (i * 256 + tid) * 16;
    int e = o >> 1;
    int row = e >> 5, col = e & 31;
    gload16(A + (size_t)(bm + row) * K + col, (char*)sA[0] + o);
    gload16(B + (size_t)(bn + row) * K + col, (char*)sB[0] + o);
  }

  int buf = 0;
  for (int k0 = 0; k0 < K; k0 += 32, buf ^= 1) {
    __syncthreads();
    if (k0 + 32 < K) {
#pragma unroll
      for (int i = 0; i < 2; ++i) {
        int o = (i * 256 + tid) * 16;
        int e = o >> 1;
        int row = e >> 5, col = e & 31;
        gload16(A + (size_t)(bm + row) * K + k0 + 32 + col, (char*)sA[buf ^ 1] + o);
        gload16(B + (size_t)(bn + row) * K + k0 + 32 + col, (char*)sB[buf ^ 1] + o);
      }
    }
    bf16x8 af[4], bfr[4];
#pragma unroll
    for (int i = 0; i < 4; ++i) {
      af[i]  = *(const bf16x8*)&sA[buf][(wr + i * 16 + ln) * 32 + quad * 8];
      bfr[i] = *(const bf16x8*)&sB[buf][(wc + i * 16 + ln) * 32 + quad * 8];
    }
#pragma unroll
    for (int i = 0; i < 4; ++i)
#pragma unroll
      for (int j = 0; j < 4; ++j)
        acc[i][j] = __builtin_amdgcn_mfma_f32_16x16x32_bf16(af[i], bfr[j], acc[i][j], 0, 0, 0);
  }

  const int bufi = bn >> 10;                  // 0:q 1:k 2:v (block-uniform)
  const int hq = ((bn & 1023) + wc) >> 6;     // head, wave-uniform
  if (bufi < 2) {
    // ---- q/k with fused RoPE ----
    unsigned short* const base = bufi == 0 ? dq : dk;
    const float qsc = bufi == 0 ? 0.180336880f : 1.0f;  // (1/8)*log2(e) for q
#pragma unroll
    for (int i = 0; i < 4; ++i)
#pragma unroll
      for (int j = 0; j < 4; ++j) {
        int n = bn + wc + j * 16 + ln;
        float bi = bias[n];
        int hd = j * 16 + ln;
        int pi = hd >> 1;
        bool evn = (ln & 1) == 0;
#pragma unroll
        for (int r = 0; r < 4; ++r) {
          int m = bm + wr + i * 16 + quad * 4 + r;
          float val = acc[i][j][r] + bi;
          float par = __shfl_xor(val, 1);
          float c = fc[m * 32 + pi], sn = fs[m * 32 + pi];
          float o = evn ? (val * c - par * sn) : (par * sn + val * c);
          base[((size_t)(hq * S_LEN + m)) * HD + hd] = f2b(o * qsc);
        }
      }
  } else {
    // ---- v: write transposed (h,hd,s) via per-wave LDS scratch ----
    __syncthreads();
    unsigned short* scr =
        (wave < 2 ? (unsigned short*)sA : (unsigned short*)sB) + (wave & 1) * 4096;
#pragma unroll
    for (int i = 0; i < 4; ++i)
#pragma unroll
      for (int j = 0; j < 4; ++j) {
        int n = bn + wc + j * 16 + ln;
        float bi = bias[n];
        int hd = j * 16 + ln;
#pragma unroll
        for (int r = 0; r < 4; ++r) {
          int sl = i * 16 + quad * 4 + r;
          int byte = hd * 128 + ((((sl >> 3) ^ (hd & 7)) << 4)) + (sl & 7) * 2;
          *(unsigned short*)((char*)scr + byte) = f2b(acc[i][j][r] + bi);
        }
      }
#pragma unroll
    for (int pass = 0; pass < 4; ++pass) {
      int row = pass * 16 + ln;
      uint4 d0 = *(uint4*)((char*)scr + row * 128 + (((quad * 2) ^ (row & 7)) << 4));
      uint4 d1 = *(uint4*)((char*)scr + row * 128 + (((quad * 2 + 1) ^ (row & 7)) << 4));
      uint4* dst = (uint4*)(vtout + ((size_t)(hq * HD + row)) * S_LEN + bm + wr + quad * 16);
      dst[0] = d0;
      dst[1] = d1;
    }
  }
}

// ---------------- gemm2: out-proj NT GEMM, 128x64 tile, f32 out -------------------
// grid (32,16) = 512 blocks = 2/CU (vs old 128x128 @ 256 blocks = 1/CU, 4 waves).
__global__ __launch_bounds__(256) void gemm_out(
    const unsigned short* __restrict__ A, const unsigned short* __restrict__ B,
    const float* __restrict__ bias, float* __restrict__ outF, int N, int K) {
  __shared__ alignas(16) unsigned short sA[2][128 * 32];
  __shared__ alignas(16) unsigned short sB[2][64 * 32];
  const int tid = threadIdx.x;
  const int lane = tid & 63, wave = tid >> 6;
  const int ln = lane & 15, quad = lane >> 4;
  const int bm = blockIdx.x * 128, bn = blockIdx.y * 64;
  const int wr = (wave >> 1) * 64, wc = (wave & 1) * 32;

  f32x4 acc[4][2];
#pragma unroll
  for (int i = 0; i < 4; ++i)
#pragma unroll
    for (int j = 0; j < 2; ++j) acc[i][j] = fzero4();

  {
#pragma unroll
    for (int i = 0; i < 2; ++i) {
      int o = (i * 256 + tid) * 16;
      int e = o >> 1;
      int row = e >> 5, col = e & 31;
      gload16(A + (size_t)(bm + row) * K + col, (char*)sA[0] + o);
    }
    int o = tid * 16;
    int e = o >> 1;
    int row = e >> 5, col = e & 31;
    gload16(B + (size_t)(bn + row) * K + col, (char*)sB[0] + o);
  }

  int buf = 0;
  for (int k0 = 0; k0 < K; k0 += 32, buf ^= 1) {
    __syncthreads();
    if (k0 + 32 < K) {
#pragma unroll
      for (int i = 0; i < 2; ++i) {
        int o = (i * 256 + tid) * 16;
        int e = o >> 1;
        int row = e >> 5, col = e & 31;
        gload16(A + (size_t)(bm + row) * K + k0 + 32 + col, (char*)sA[buf ^ 1] + o);
      }
      int o = tid * 16;
      int e = o >> 1;
      int row = e >> 5, col = e & 31;
      gload16(B + (size_t)(bn + row) * K + k0 + 32 + col, (char*)sB[buf ^ 1] + o);
    }
    bf16x8 af[4], bfr[2];
#pragma unroll
    for (int i = 0; i < 4; ++i)
      af[i] = *(const bf16x8*)&sA[buf][(wr + i * 16 + ln) * 32 + quad * 8];
#pragma unroll
    for (int j = 0; j < 2; ++j)
      bfr[j] = *(const bf16x8*)&sB[buf][(wc + j * 16 + ln) * 32 + quad * 8];
#pragma unroll
    for (int i = 0; i < 4; ++i)
#pragma unroll
      for (int j = 0; j < 2; ++j)
        acc[i][j] = __builtin_amdgcn_mfma_f32_16x16x32_bf16(af[i], bfr[j], acc[i][j], 0, 0, 0);
  }

#pragma unroll
  for (int i = 0; i < 4; ++i)
#pragma unroll
    for (int j = 0; j < 2; ++j) {
      int n = bn + wc + j * 16 + ln;
      float bi = bias[n];
#pragma unroll
      for (int r = 0; r < 4; ++r) {
        int m = bm + wr + i * 16 + quad * 4 + r;
        outF[(size_t)m * N + n] = acc[i][j][r] + bi;
      }
    }
}

// ---------------- LDS swizzled 16B reads (chunk XOR to spread banks) ----------------
__device__ __forceinline__ bf16x8 lds_swzK(const unsigned short* s, int row, int chunk) {
  int byte = row * 128 + ((chunk ^ ((row >> 2) & 7)) << 4);
  return *(const bf16x8*)((const char*)s + byte);
}
__device__ __forceinline__ bf16x8 lds_swzV(const unsigned short* s, int row, int chunk) {
  int byte = row * 128 + ((chunk ^ (row & 7)) << 4);
  return *(const bf16x8*)((const char*)s + byte);
}

// ---------------- Flash attention, causal, exp2 softmax (no running max) ----------
// R8 pair structure (uniform 65 kv-steps/block) + two fixes:
//  (1) K+V ping-pong staging: one barrier/tile, DMA for t+1 issued post-barrier ->
//      the ~900cyc drain (R8: exposed every tile) hides behind tile-t compute.
//  (2) XCD-aware swizzle: 1-D grid 512, h = 2*(c&7)+((c>>3)&1), xp = c>>4. Under
//      round-robin XCD dispatch each XCD serves 2 heads -> 2MB KV fits its 4MB L2
//      (R8 FETCH=212MB was 16-head thrash).
__global__ __launch_bounds__(256, 4) void flash_kernel(
    const unsigned short* __restrict__ qg, const unsigned short* __restrict__ kg,
    const unsigned short* __restrict__ vtg, unsigned short* __restrict__ attn) {
  __shared__ alignas(16) unsigned short sK[2][64 * 64];
  __shared__ alignas(16) unsigned short sV[2][64 * 64];
  __shared__ alignas(16) unsigned short sP[4 * 16 * 72];  // per-wave 16x64, stride 72

  const int tid = threadIdx.x;
  const int lane = tid & 63, wave = tid >> 6;
  const int ln = lane & 15, quad = lane >> 4;
  const int c = blockIdx.x;
  const int h = 2 * (c & 7) + ((c >> 3) & 1);
  const int xp = c >> 4;

  const unsigned short* qh = qg + (size_t)h * (S_LEN * HD);
  const unsigned short* kh = kg + (size_t)h * (S_LEN * HD);
  const unsigned short* vh = vtg + (size_t)h * (HD * S_LEN);

  bf16x8 ones;
#pragma unroll
  for (int j = 0; j < 8; ++j) ones[j] = (short)0x3F80;  // bf16 1.0
  unsigned short* pw = &sP[wave * (16 * 72)];

  for (int p = 0; p < 2; ++p) {
    const int qb = p == 0 ? xp : 63 - xp;
    const int q0 = qb * 64;
    const int qrow = q0 + wave * 16;

    bf16x8 qf[2];
    qf[0] = *(const bf16x8*)(qh + (size_t)(qrow + ln) * HD + quad * 8);
    qf[1] = *(const bf16x8*)(qh + (size_t)(qrow + ln) * HD + 32 + quad * 8);

    f32x4 o_acc[4];
    f32x4 l_acc = fzero4();
#pragma unroll
    for (int t = 0; t < 4; ++t) o_acc[t] = fzero4();

    const int nkv = qb + 1;

    // preload kv tile 0 into buffer 0 (barrier first: pass-0 readers of these
    // buffers must be done before overwrite)
    __syncthreads();
#pragma unroll
    for (int i = 0; i < 2; ++i) {
      int ob = (i * 256 + tid) * 16;
      int row = ob >> 7;
      int ch = (ob >> 4) & 7;
      gload16(kh + (size_t)row * HD + ((ch ^ ((row >> 2) & 7)) << 3), (char*)sK[0] + ob);
      gload16(vh + (size_t)row * S_LEN + ((ch ^ (row & 7)) << 3), (char*)sV[0] + ob);
    }

    int buf = 0;
    for (int kt = 0; kt < nkv; ++kt, buf ^= 1) {
      const int kv0 = kt * 64;
      __syncthreads();  // drains DMA for buf (issued a full tile ago); guards buf^1
      if (kt + 1 < nkv) {
        const int kv1 = kv0 + 64;
#pragma unroll
        for (int i = 0; i < 2; ++i) {
          int ob = (i * 256 + tid) * 16;
          int row = ob >> 7;
          int ch = (ob >> 4) & 7;
          gload16(kh + (size_t)(kv1 + row) * HD + ((ch ^ ((row >> 2) & 7)) << 3),
                  (char*)sK[buf ^ 1] + ob);
          gload16(vh + (size_t)row * S_LEN + kv1 + ((ch ^ (row & 7)) << 3),
                  (char*)sV[buf ^ 1] + ob);
        }
      }

      // S = Q K^T (tile t col ln <-> kv row 4*ln+t)
      const unsigned short* kp = sK[buf];
      const unsigned short* vp = sV[buf];
      f32x4 sc[4];
#pragma unroll
      for (int t = 0; t < 4; ++t) sc[t] = fzero4();
#pragma unroll
      for (int t = 0; t < 4; ++t) {
        int krow = ln * 4 + t;
        bf16x8 kb0 = lds_swzK(kp, krow, quad);
        bf16x8 kb1 = lds_swzK(kp, krow, 4 + quad);
        sc[t] = __builtin_amdgcn_mfma_f32_16x16x32_bf16(qf[0], kb0, sc[t], 0, 0, 0);
        sc[t] = __builtin_amdgcn_mfma_f32_16x16x32_bf16(qf[1], kb1, sc[t], 0, 0, 0);
      }

      // p = exp2(s); mask only on diagonal tile; truncation pack; b64 LDS writes
      if (kt == nkv - 1) {
#pragma unroll
        for (int r = 0; r < 4; ++r) {
          int row = qrow + quad * 4 + r;
          int colb = kv0 + ln * 4;
          float p0 = (colb + 0 <= row) ? __builtin_amdgcn_exp2f(sc[0][r]) : 0.0f;
          float p1 = (colb + 1 <= row) ? __builtin_amdgcn_exp2f(sc[1][r]) : 0.0f;
          float p2 = (colb + 2 <= row) ? __builtin_amdgcn_exp2f(sc[2][r]) : 0.0f;
          float p3 = (colb + 3 <= row) ? __builtin_amdgcn_exp2f(sc[3][r]) : 0.0f;
          *(uint2*)&pw[(quad * 4 + r) * 72 + ln * 4] = make_uint2(pk2t(p0, p1), pk2t(p2, p3));
        }
      } else {
#pragma unroll
        for (int r = 0; r < 4; ++r) {
          float p0 = __builtin_amdgcn_exp2f(sc[0][r]);
          float p1 = __builtin_amdgcn_exp2f(sc[1][r]);
          float p2 = __builtin_amdgcn_exp2f(sc[2][r]);
          float p3 = __builtin_amdgcn_exp2f(sc[3][r]);
          *(uint2*)&pw[(quad * 4 + r) * 72 + ln * 4] = make_uint2(pk2t(p0, p1), pk2t(p2, p3));
        }
      }

      // P fragments (A-layout), per-wave region -> no barrier needed
      bf16x8 pa0 = *(const bf16x8*)&pw[ln * 72 + quad * 8];
      bf16x8 pa1 = *(const bf16x8*)&pw[ln * 72 + 32 + quad * 8];

      // l += P @ ones
      l_acc = __builtin_amdgcn_mfma_f32_16x16x32_bf16(pa0, ones, l_acc, 0, 0, 0);
      l_acc = __builtin_amdgcn_mfma_f32_16x16x32_bf16(pa1, ones, l_acc, 0, 0, 0);

      // O += P @ V
#pragma unroll
      for (int t = 0; t < 4; ++t) {
        int vrow = t * 16 + ln;
        bf16x8 vb0 = lds_swzV(vp, vrow, quad);
        bf16x8 vb1 = lds_swzV(vp, vrow, 4 + quad);
        o_acc[t] = __builtin_amdgcn_mfma_f32_16x16x32_bf16(pa0, vb0, o_acc[t], 0, 0, 0);
        o_acc[t] = __builtin_amdgcn_mfma_f32_16x16x32_bf16(pa1, vb1, o_acc[t], 0, 0, 0);
      }
    }

    // epilogue for this tile: attn[s, h*64+hd] = O/l (bf16)
    float inv[4];
#pragma unroll
    for (int r = 0; r < 4; ++r) inv[r] = 1.0f / l_acc[r];
#pragma unroll
    for (int t = 0; t < 4; ++t)
#pragma unroll
      for (int r = 0; r < 4; ++r) {
        int row = qrow + quad * 4 + r;
        attn[(size_t)row * DIM + h * HD + t * 16 + ln] = f2b(o_acc[t][r] * inv[r]);
      }
  }
}

extern "C" void kernel_launch(void* const* d_in, const int* in_sizes, int n_in,
                              void* d_out, int out_size, void* d_ws, size_t ws_size,
                              hipStream_t stream) {
  const float* x    = (const float*)d_in[0];
  const float* fc   = (const float*)d_in[2];
  const float* fs   = (const float*)d_in[3];
  const float* wqw  = (const float*)d_in[5];
  const float* wqb  = (const float*)d_in[6];
  const float* wkw  = (const float*)d_in[7];
  const float* wkb  = (const float*)d_in[8];
  const float* wvw  = (const float*)d_in[9];
  const float* wvb  = (const float*)d_in[10];
  const float* wow  = (const float*)d_in[11];
  const float* wobf = (const float*)d_in[12];
  float* out = (float*)d_out;

  char* ws = (char*)d_ws;
  const size_t MB = (size_t)1 << 20;
  unsigned short* xb    = (unsigned short*)(ws + 0);
  unsigned short* wqkvb = (unsigned short*)(ws + 8 * MB);
  unsigned short* wobb  = (unsigned short*)(ws + 16 * MB);
  float* biasq = (float*)(ws + 18 * MB);
  float* biaso = (float*)(ws + 18 * MB + 65536);
  unsigned short* qb_ = (unsigned short*)(ws + 19 * MB);
  unsigned short* kb_ = (unsigned short*)(ws + 27 * MB);
  unsigned short* vt  = (unsigned short*)(ws + 35 * MB);  // vT written by gemm1
  unsigned short* attn = (unsigned short*)(ws + 0);       // aliases xb (dead after gemm1)

  cvt_all<<<8196, 256, 0, stream>>>(x, wqw, wkw, wvw, wow, wqb, wkb, wvb, wobf,
                                    xb, wqkvb, wobb, biasq, biaso);
  gemm_qkv<<<dim3(32, 24), 256, 0, stream>>>(xb, wqkvb, biasq, qb_, kb_, vt, fc, fs, 1024);
  flash_kernel<<<512, 256, 0, stream>>>(qb_, kb_, vt, attn);
  gemm_out<<<dim3(32, 16), 256, 0, stream>>>(attn, wobb, biaso, out, 1024, 1024);
}

// Round 10
// 267.430 us; speedup vs baseline: 1.1127x; 1.0012x over previous
//
#include <hip/hip_runtime.h>

// AttentionLoRA: B=1, S=4096, D=1024, H=16, HD=64.
// Pipeline (4 kernels):
//   cvt_all (f32->bf16 + bias pack)
//   gemm1: QKV NT-GEMM, epilogue fuses RoPE (q/k) and V-transpose -> vT (h,hd,s)
//   flash: causal, exp2 softmax; 8-wave blocks: wave-group 0 -> q-tile a,
//          group 1 -> q-tile 63-a, SHARED K/V ping-pong staging (one sweep of
//          64-a kv tiles). Blocks c,c+256 (same CU) get a=u,31-u -> 97 staged
//          steps/CU uniform; XCD swizzle keeps 2 heads per XCD (L2-resident KV).
//   gemm2: out-proj, 128x64 tiles (512 blocks, 2/CU), f32 out.

#define S_LEN 4096
#define DIM   1024
#define NH    16
#define HD    64

typedef __attribute__((ext_vector_type(8))) short bf16x8;   // 8 bf16 = 4 VGPRs
typedef __attribute__((ext_vector_type(4))) float f32x4;

__device__ __forceinline__ unsigned short f2b(float f) {
  union { float f; unsigned int u; } v; v.f = f;
  unsigned int r = (v.u + 0x7fffu + ((v.u >> 16) & 1u)) >> 16;  // RNE
  return (unsigned short)r;
}
__device__ __forceinline__ float b2f(unsigned short h) {
  union { unsigned int u; float f; } v; v.u = ((unsigned int)h) << 16;
  return v.f;
}
// pack two f32 -> two bf16 by truncation (p in [0,1]; <=1ulp)
__device__ __forceinline__ unsigned int pk2t(float a, float b) {
  union { float f; unsigned int u; } x, y; x.f = a; y.f = b;
  return (x.u >> 16) | (y.u & 0xffff0000u);
}
__device__ __forceinline__ void gload16(const void* g, void* l) {
  __builtin_amdgcn_global_load_lds(
      (const __attribute__((address_space(1))) unsigned int*)g,
      (__attribute__((address_space(3))) unsigned int*)l, 16, 0, 0);
}
__device__ __forceinline__ f32x4 fzero4() { f32x4 z = {0.f, 0.f, 0.f, 0.f}; return z; }

// ---------------- fused f32->bf16 convert (x, wq, wk, wv, wo) + bias pack ----------
__global__ void cvt_all(const float* __restrict__ x, const float* __restrict__ wq,
                        const float* __restrict__ wk, const float* __restrict__ wv,
                        const float* __restrict__ wo, const float* __restrict__ qb,
                        const float* __restrict__ kb, const float* __restrict__ vbs,
                        const float* __restrict__ ob, unsigned short* __restrict__ xb,
                        unsigned short* __restrict__ wqkvb, unsigned short* __restrict__ wobb,
                        float* __restrict__ biasq, float* __restrict__ biaso) {
  int i = blockIdx.x * 256 + threadIdx.x;  // float4 index
  if (i < 2097152) {
    const float* src; unsigned short* dst; int off;
    if (i < 1048576)      { src = x;  dst = xb;              off = i; }
    else if (i < 1310720) { src = wq; dst = wqkvb;           off = i - 1048576; }
    else if (i < 1572864) { src = wk; dst = wqkvb + 1048576; off = i - 1310720; }
    else if (i < 1835008) { src = wv; dst = wqkvb + 2097152; off = i - 1572864; }
    else                  { src = wo; dst = wobb;            off = i - 1835008; }
    float4 v = ((const float4*)src)[off];
    unsigned int lo = (unsigned int)f2b(v.x) | ((unsigned int)f2b(v.y) << 16);
    unsigned int hi = (unsigned int)f2b(v.z) | ((unsigned int)f2b(v.w) << 16);
    ((uint2*)dst)[off] = make_uint2(lo, hi);
  } else if (i < 2097152 + 1024) {
    int j = i - 2097152;
    if (j < 256)      ((float4*)biasq)[j]              = ((const float4*)qb)[j];
    else if (j < 512) ((float4*)(biasq + 1024))[j-256] = ((const float4*)kb)[j-256];
    else if (j < 768) ((float4*)(biasq + 2048))[j-512] = ((const float4*)vbs)[j-512];
    else              ((float4*)biaso)[j-768]          = ((const float4*)ob)[j-768];
  }
}

// ---------------- gemm1: QKV NT-GEMM with fused RoPE + V-transpose epilogue -------
// 128x128 tile, BK=32, 4 waves each 64x64. Ping-pong LDS staging, 1 barrier/K-iter.
__global__ __launch_bounds__(256) void gemm_qkv(
    const unsigned short* __restrict__ A, const unsigned short* __restrict__ B,
    const float* __restrict__ bias, unsigned short* __restrict__ dq,
    unsigned short* __restrict__ dk, unsigned short* __restrict__ vtout,
    const float* __restrict__ fc, const float* __restrict__ fs, int K) {
  __shared__ alignas(16) unsigned short sA[2][128 * 32];
  __shared__ alignas(16) unsigned short sB[2][128 * 32];
  const int tid = threadIdx.x;
  const int lane = tid & 63, wave = tid >> 6;
  const int ln = lane & 15, quad = lane >> 4;
  const int bm = blockIdx.x * 128, bn = blockIdx.y * 128;
  const int wr = (wave >> 1) * 64, wc = (wave & 1) * 64;

  f32x4 acc[4][4];
#pragma unroll
  for (int i = 0; i < 4; ++i)
#pragma unroll
    for (int j = 0; j < 4; ++j) acc[i][j] = fzero4();

#pragma unroll
  for (int i = 0; i < 2; ++i) {
    int o = (i * 256 + tid) * 16;
    int e = o >> 1;
    int row = e >> 5, col = e & 31;
    gload16(A + (size_t)(bm + row) * K + col, (char*)sA[0] + o);
    gload16(B + (size_t)(bn + row) * K + col, (char*)sB[0] + o);
  }

  int buf = 0;
  for (int k0 = 0; k0 < K; k0 += 32, buf ^= 1) {
    __syncthreads();
    if (k0 + 32 < K) {
#pragma unroll
      for (int i = 0; i < 2; ++i) {
        int o = (i * 256 + tid) * 16;
        int e = o >> 1;
        int row = e >> 5, col = e & 31;
        gload16(A + (size_t)(bm + row) * K + k0 + 32 + col, (char*)sA[buf ^ 1] + o);
        gload16(B + (size_t)(bn + row) * K + k0 + 32 + col, (char*)sB[buf ^ 1] + o);
      }
    }
    bf16x8 af[4], bfr[4];
#pragma unroll
    for (int i = 0; i < 4; ++i) {
      af[i]  = *(const bf16x8*)&sA[buf][(wr + i * 16 + ln) * 32 + quad * 8];
      bfr[i] = *(const bf16x8*)&sB[buf][(wc + i * 16 + ln) * 32 + quad * 8];
    }
#pragma unroll
    for (int i = 0; i < 4; ++i)
#pragma unroll
      for (int j = 0; j < 4; ++j)
        acc[i][j] = __builtin_amdgcn_mfma_f32_16x16x32_bf16(af[i], bfr[j], acc[i][j], 0, 0, 0);
  }

  const int bufi = bn >> 10;                  // 0:q 1:k 2:v (block-uniform)
  const int hq = ((bn & 1023) + wc) >> 6;     // head, wave-uniform
  if (bufi < 2) {
    // ---- q/k with fused RoPE ----
    unsigned short* const base = bufi == 0 ? dq : dk;
    const float qsc = bufi == 0 ? 0.180336880f : 1.0f;  // (1/8)*log2(e) for q
#pragma unroll
    for (int i = 0; i < 4; ++i)
#pragma unroll
      for (int j = 0; j < 4; ++j) {
        int n = bn + wc + j * 16 + ln;
        float bi = bias[n];
        int hd = j * 16 + ln;
        int pi = hd >> 1;
        bool evn = (ln & 1) == 0;
#pragma unroll
        for (int r = 0; r < 4; ++r) {
          int m = bm + wr + i * 16 + quad * 4 + r;
          float val = acc[i][j][r] + bi;
          float par = __shfl_xor(val, 1);
          float c = fc[m * 32 + pi], sn = fs[m * 32 + pi];
          float o = evn ? (val * c - par * sn) : (par * sn + val * c);
          base[((size_t)(hq * S_LEN + m)) * HD + hd] = f2b(o * qsc);
        }
      }
  } else {
    // ---- v: write transposed (h,hd,s) via per-wave LDS scratch ----
    __syncthreads();
    unsigned short* scr =
        (wave < 2 ? (unsigned short*)sA : (unsigned short*)sB) + (wave & 1) * 4096;
#pragma unroll
    for (int i = 0; i < 4; ++i)
#pragma unroll
      for (int j = 0; j < 4; ++j) {
        int n = bn + wc + j * 16 + ln;
        float bi = bias[n];
        int hd = j * 16 + ln;
#pragma unroll
        for (int r = 0; r < 4; ++r) {
          int sl = i * 16 + quad * 4 + r;
          int byte = hd * 128 + ((((sl >> 3) ^ (hd & 7)) << 4)) + (sl & 7) * 2;
          *(unsigned short*)((char*)scr + byte) = f2b(acc[i][j][r] + bi);
        }
      }
#pragma unroll
    for (int pass = 0; pass < 4; ++pass) {
      int row = pass * 16 + ln;
      uint4 d0 = *(uint4*)((char*)scr + row * 128 + (((quad * 2) ^ (row & 7)) << 4));
      uint4 d1 = *(uint4*)((char*)scr + row * 128 + (((quad * 2 + 1) ^ (row & 7)) << 4));
      uint4* dst = (uint4*)(vtout + ((size_t)(hq * HD + row)) * S_LEN + bm + wr + quad * 16);
      dst[0] = d0;
      dst[1] = d1;
    }
  }
}

// ---------------- gemm2: out-proj NT GEMM, 128x64 tile, f32 out -------------------
__global__ __launch_bounds__(256) void gemm_out(
    const unsigned short* __restrict__ A, const unsigned short* __restrict__ B,
    const float* __restrict__ bias, float* __restrict__ outF, int N, int K) {
  __shared__ alignas(16) unsigned short sA[2][128 * 32];
  __shared__ alignas(16) unsigned short sB[2][64 * 32];
  const int tid = threadIdx.x;
  const int lane = tid & 63, wave = tid >> 6;
  const int ln = lane & 15, quad = lane >> 4;
  const int bm = blockIdx.x * 128, bn = blockIdx.y * 64;
  const int wr = (wave >> 1) * 64, wc = (wave & 1) * 32;

  f32x4 acc[4][2];
#pragma unroll
  for (int i = 0; i < 4; ++i)
#pragma unroll
    for (int j = 0; j < 2; ++j) acc[i][j] = fzero4();

  {
#pragma unroll
    for (int i = 0; i < 2; ++i) {
      int o = (i * 256 + tid) * 16;
      int e = o >> 1;
      int row = e >> 5, col = e & 31;
      gload16(A + (size_t)(bm + row) * K + col, (char*)sA[0] + o);
    }
    int o = tid * 16;
    int e = o >> 1;
    int row = e >> 5, col = e & 31;
    gload16(B + (size_t)(bn + row) * K + col, (char*)sB[0] + o);
  }

  int buf = 0;
  for (int k0 = 0; k0 < K; k0 += 32, buf ^= 1) {
    __syncthreads();
    if (k0 + 32 < K) {
#pragma unroll
      for (int i = 0; i < 2; ++i) {
        int o = (i * 256 + tid) * 16;
        int e = o >> 1;
        int row = e >> 5, col = e & 31;
        gload16(A + (size_t)(bm + row) * K + k0 + 32 + col, (char*)sA[buf ^ 1] + o);
      }
      int o = tid * 16;
      int e = o >> 1;
      int row = e >> 5, col = e & 31;
      gload16(B + (size_t)(bn + row) * K + k0 + 32 + col, (char*)sB[buf ^ 1] + o);
    }
    bf16x8 af[4], bfr[2];
#pragma unroll
    for (int i = 0; i < 4; ++i)
      af[i] = *(const bf16x8*)&sA[buf][(wr + i * 16 + ln) * 32 + quad * 8];
#pragma unroll
    for (int j = 0; j < 2; ++j)
      bfr[j] = *(const bf16x8*)&sB[buf][(wc + j * 16 + ln) * 32 + quad * 8];
#pragma unroll
    for (int i = 0; i < 4; ++i)
#pragma unroll
      for (int j = 0; j < 2; ++j)
        acc[i][j] = __builtin_amdgcn_mfma_f32_16x16x32_bf16(af[i], bfr[j], acc[i][j], 0, 0, 0);
  }

#pragma unroll
  for (int i = 0; i < 4; ++i)
#pragma unroll
    for (int j = 0; j < 2; ++j) {
      int n = bn + wc + j * 16 + ln;
      float bi = bias[n];
#pragma unroll
      for (int r = 0; r < 4; ++r) {
        int m = bm + wr + i * 16 + quad * 4 + r;
        outF[(size_t)m * N + n] = acc[i][j][r] + bi;
      }
    }
}

// ---------------- LDS swizzled 16B reads (chunk XOR to spread banks) ----------------
__device__ __forceinline__ bf16x8 lds_swzK(const unsigned short* s, int row, int chunk) {
  int byte = row * 128 + ((chunk ^ ((row >> 2) & 7)) << 4);
  return *(const bf16x8*)((const char*)s + byte);
}
__device__ __forceinline__ bf16x8 lds_swzV(const unsigned short* s, int row, int chunk) {
  int byte = row * 128 + ((chunk ^ (row & 7)) << 4);
  return *(const bf16x8*)((const char*)s + byte);
}

// ---------------- Flash attention, causal, exp2 softmax (no running max) ----------
// 8-wave (512-thread) blocks: wave-group 0 (waves 0-3) computes q-tile a, group 1
// (waves 4-7) q-tile 63-a, sharing ONE ping-pong K/V staging sweep of 64-a tiles
// (group 0 'continue's past its diagonal but still hits every barrier).
// Per-block compute = 4*(a+1)+4*(64-a) = 260 wave-tiles, uniform. Same-CU pair
// (c, c+256) gets a = u, 31-u -> 97 staged steps/CU uniform. 16 waves/CU (vs R9's
// 8 — R9 was issue-bound at 2 waves/SIMD: VALU 39%, MFMA 21%, no pipe saturated).
// XCD swizzle h = 2*(c&7)+((c>>3)&1): 2 heads/XCD -> KV L2-resident (R9: FETCH
// 212->12MB). Score col ln of tile t <-> kv row 4*ln+t; l via MFMA-with-ones.
__global__ __launch_bounds__(512, 2) void flash_kernel(
    const unsigned short* __restrict__ qg, const unsigned short* __restrict__ kg,
    const unsigned short* __restrict__ vtg, unsigned short* __restrict__ attn) {
  __shared__ alignas(16) unsigned short sK[2][64 * 64];
  __shared__ alignas(16) unsigned short sV[2][64 * 64];
  __shared__ alignas(16) unsigned short sP[8 * 16 * 72];  // per-wave 16x64, stride 72

  const int tid = threadIdx.x;
  const int lane = tid & 63, wave = tid >> 6;
  const int w = wave & 3, grp = wave >> 2;
  const int ln = lane & 15, quad = lane >> 4;
  const int c = blockIdx.x;
  const int h = 2 * (c & 7) + ((c >> 3) & 1);
  const int u = c >> 4;                 // 0..31
  const int a = (u < 16) ? u : 47 - u;  // pair (u, u+16) -> (a, 31-a): uniform CU sum
  const int q0 = (grp == 0 ? a : 63 - a) * 64;
  const int qrow = q0 + w * 16;

  const unsigned short* qh = qg + (size_t)h * (S_LEN * HD);
  const unsigned short* kh = kg + (size_t)h * (S_LEN * HD);
  const unsigned short* vh = vtg + (size_t)h * (HD * S_LEN);

  bf16x8 qf[2];
  qf[0] = *(const bf16x8*)(qh + (size_t)(qrow + ln) * HD + quad * 8);
  qf[1] = *(const bf16x8*)(qh + (size_t)(qrow + ln) * HD + 32 + quad * 8);

  f32x4 o_acc[4];
  f32x4 l_acc = fzero4();
#pragma unroll
  for (int t = 0; t < 4; ++t) o_acc[t] = fzero4();
  bf16x8 ones;
#pragma unroll
  for (int j = 0; j < 8; ++j) ones[j] = (short)0x3F80;  // bf16 1.0
  unsigned short* pw = &sP[wave * (16 * 72)];

  const int nkv = 64 - a;  // shared sweep length (covers group 1's diagonal)
  const int srow = tid >> 3, sch = tid & 7;  // 512-thread staging: 1 K + 1 V gload16 each

  // preload kv tile 0 into buffer 0 (no prior readers)
  gload16(kh + (size_t)srow * HD + ((sch ^ ((srow >> 2) & 7)) << 3), (char*)sK[0] + tid * 16);
  gload16(vh + (size_t)srow * S_LEN + ((sch ^ (srow & 7)) << 3), (char*)sV[0] + tid * 16);

  int buf = 0;
  for (int kt = 0; kt < nkv; ++kt, buf ^= 1) {
    const int kv0 = kt * 64;
    __syncthreads();  // drains DMA for buf (issued a full tile ago); guards buf^1
    if (kt + 1 < nkv) {
      const int kv1 = kv0 + 64;
      gload16(kh + (size_t)(kv1 + srow) * HD + ((sch ^ ((srow >> 2) & 7)) << 3),
              (char*)sK[buf ^ 1] + tid * 16);
      gload16(vh + (size_t)srow * S_LEN + kv1 + ((sch ^ (srow & 7)) << 3),
              (char*)sV[buf ^ 1] + tid * 16);
    }
    if (kv0 > qrow + 15) continue;  // wave entirely above tile (barrier already done)

    // S = Q K^T (tile t col ln <-> kv row 4*ln+t)
    const unsigned short* kp = sK[buf];
    const unsigned short* vp = sV[buf];
    f32x4 sc[4];
#pragma unroll
    for (int t = 0; t < 4; ++t) sc[t] = fzero4();
#pragma unroll
    for (int t = 0; t < 4; ++t) {
      int krow = ln * 4 + t;
      bf16x8 kb0 = lds_swzK(kp, krow, quad);
      bf16x8 kb1 = lds_swzK(kp, krow, 4 + quad);
      sc[t] = __builtin_amdgcn_mfma_f32_16x16x32_bf16(qf[0], kb0, sc[t], 0, 0, 0);
      sc[t] = __builtin_amdgcn_mfma_f32_16x16x32_bf16(qf[1], kb1, sc[t], 0, 0, 0);
    }

    // p = exp2(s); mask only on the group's diagonal tile (kv0 == q0)
    if (kv0 == q0) {
#pragma unroll
      for (int r = 0; r < 4; ++r) {
        int row = qrow + quad * 4 + r;
        int colb = kv0 + ln * 4;
        float p0 = (colb + 0 <= row) ? __builtin_amdgcn_exp2f(sc[0][r]) : 0.0f;
        float p1 = (colb + 1 <= row) ? __builtin_amdgcn_exp2f(sc[1][r]) : 0.0f;
        float p2 = (colb + 2 <= row) ? __builtin_amdgcn_exp2f(sc[2][r]) : 0.0f;
        float p3 = (colb + 3 <= row) ? __builtin_amdgcn_exp2f(sc[3][r]) : 0.0f;
        *(uint2*)&pw[(quad * 4 + r) * 72 + ln * 4] = make_uint2(pk2t(p0, p1), pk2t(p2, p3));
      }
    } else {
#pragma unroll
      for (int r = 0; r < 4; ++r) {
        float p0 = __builtin_amdgcn_exp2f(sc[0][r]);
        float p1 = __builtin_amdgcn_exp2f(sc[1][r]);
        float p2 = __builtin_amdgcn_exp2f(sc[2][r]);
        float p3 = __builtin_amdgcn_exp2f(sc[3][r]);
        *(uint2*)&pw[(quad * 4 + r) * 72 + ln * 4] = make_uint2(pk2t(p0, p1), pk2t(p2, p3));
      }
    }

    // P fragments (A-layout), per-wave region -> no barrier needed
    bf16x8 pa0 = *(const bf16x8*)&pw[ln * 72 + quad * 8];
    bf16x8 pa1 = *(const bf16x8*)&pw[ln * 72 + 32 + quad * 8];

    // l += P @ ones
    l_acc = __builtin_amdgcn_mfma_f32_16x16x32_bf16(pa0, ones, l_acc, 0, 0, 0);
    l_acc = __builtin_amdgcn_mfma_f32_16x16x32_bf16(pa1, ones, l_acc, 0, 0, 0);

    // O += P @ V
#pragma unroll
    for (int t = 0; t < 4; ++t) {
      int vrow = t * 16 + ln;
      bf16x8 vb0 = lds_swzV(vp, vrow, quad);
      bf16x8 vb1 = lds_swzV(vp, vrow, 4 + quad);
      o_acc[t] = __builtin_amdgcn_mfma_f32_16x16x32_bf16(pa0, vb0, o_acc[t], 0, 0, 0);
      o_acc[t] = __builtin_amdgcn_mfma_f32_16x16x32_bf16(pa1, vb1, o_acc[t], 0, 0, 0);
    }
  }

  // epilogue: attn[s, h*64+hd] = O/l (bf16)
  float inv[4];
#pragma unroll
  for (int r = 0; r < 4; ++r) inv[r] = 1.0f / l_acc[r];
#pragma unroll
  for (int t = 0; t < 4; ++t)
#pragma unroll
    for (int r = 0; r < 4; ++r) {
      int row = qrow + quad * 4 + r;
      attn[(size_t)row * DIM + h * HD + t * 16 + ln] = f2b(o_acc[t][r] * inv[r]);
    }
}

extern "C" void kernel_launch(void* const* d_in, const int* in_sizes, int n_in,
                              void* d_out, int out_size, void* d_ws, size_t ws_size,
                              hipStream_t stream) {
  const float* x    = (const float*)d_in[0];
  const float* fc   = (const float*)d_in[2];
  const float* fs   = (const float*)d_in[3];
  const float* wqw  = (const float*)d_in[5];
  const float* wqb  = (const float*)d_in[6];
  const float* wkw  = (const float*)d_in[7];
  const float* wkb  = (const float*)d_in[8];
  const float* wvw  = (const float*)d_in[9];
  const float* wvb  = (const float*)d_in[10];
  const float* wow  = (const float*)d_in[11];
  const float* wobf = (const float*)d_in[12];
  float* out = (float*)d_out;

  char* ws = (char*)d_ws;
  const size_t MB = (size_t)1 << 20;
  unsigned short* xb    = (unsigned short*)(ws + 0);
  unsigned short* wqkvb = (unsigned short*)(ws + 8 * MB);
  unsigned short* wobb  = (unsigned short*)(ws + 16 * MB);
  float* biasq = (float*)(ws + 18 * MB);
  float* biaso = (float*)(ws + 18 * MB + 65536);
  unsigned short* qb_ = (unsigned short*)(ws + 19 * MB);
  unsigned short* kb_ = (unsigned short*)(ws + 27 * MB);
  unsigned short* vt  = (unsigned short*)(ws + 35 * MB);  // vT written by gemm1
  unsigned short* attn = (unsigned short*)(ws + 0);       // aliases xb (dead after gemm1)

  cvt_all<<<8196, 256, 0, stream>>>(x, wqw, wkw, wvw, wow, wqb, wkb, wvb, wobf,
                                    xb, wqkvb, wobb, biasq, biaso);
  gemm_qkv<<<dim3(32, 24), 256, 0, stream>>>(xb, wqkvb, biasq, qb_, kb_, vt, fc, fs, 1024);
  flash_kernel<<<512, 512, 0, stream>>>(qb_, kb_, vt, attn);
  gemm_out<<<dim3(32, 16), 256, 0, stream>>>(attn, wobb, biaso, out, 1024, 1024);
}